// Round 1
// baseline (622.419 us; speedup 1.0000x reference)
//
#include <hip/hip_runtime.h>
#include <hip/hip_bf16.h>

#define COMMA_IDC 1010
#define NHEAD 8
#define Ll 511
#define Mrows 32704
#define MPAD 32768
#define NSEG 17

typedef __attribute__((ext_vector_type(8))) short bf16x8;
typedef __attribute__((ext_vector_type(4))) float f32x4;
typedef unsigned short u16;
typedef unsigned int u32;
typedef unsigned long long u64;

__device__ __forceinline__ u16 f2b(float f) {
  __hip_bfloat16 h = __float2bfloat16(f);
  return *reinterpret_cast<u16*>(&h);
}

__device__ __forceinline__ void gld_lds16(const void* g, void* l) {
  __builtin_amdgcn_global_load_lds(
      (const __attribute__((address_space(1))) void*)(u64)g,
      (__attribute__((address_space(3))) void*)(u32)(u64)l,
      16, 0, 0);
}

// ---- convert f32 -> bf16, slicing off token 0 : rows m=b*511+l from (b, l+1)
__global__ void conv_sliced(const float4* __restrict__ src, ushort4* __restrict__ dst) {
  int b = blockIdx.y;
  int idx = blockIdx.x * 256 + threadIdx.x;
  if (idx >= Ll * 192) return;
  int l = idx / 192, c = idx - l * 192;
  float4 v = src[(b * 512 + l + 1) * 192 + c];
  ushort4 o; o.x = f2b(v.x); o.y = f2b(v.y); o.z = f2b(v.z); o.w = f2b(v.w);
  dst[(b * Ll + l) * 192 + c] = o;
}

__global__ void conv_flat(const float4* __restrict__ src, ushort4* __restrict__ dst, int n4) {
  int i = blockIdx.x * 256 + threadIdx.x;
  if (i < n4) {
    float4 v = src[i];
    ushort4 o; o.x = f2b(v.x); o.y = f2b(v.y); o.z = f2b(v.z); o.w = f2b(v.w);
    dst[i] = o;
  }
}

__global__ void zero_kernel(float* p, int n) {
  int i = blockIdx.x * 256 + threadIdx.x;
  if (i < n) p[i] = 0.f;
}

// ---- 128x128x(K=768) bf16 MFMA GEMM, C = A @ W^T + bias.  W is [N][768] row-major.
// MODE 0: out bf16 -> Q layout [b][h][512][96]
// MODE 1: out bf16 -> K (n<768) / V (n>=768) layouts [b][h][512][96]
// MODE 2: out f32  -> of[m*768+n]
template<int MODE>
__global__ __launch_bounds__(256) void gemm128(
    const u16* __restrict__ A, const u16* __restrict__ W,
    const float* __restrict__ bias0, const float* __restrict__ bias1,
    u16* __restrict__ o0, u16* __restrict__ o1, float* __restrict__ of)
{
  __shared__ __align__(16) u16 sA[128 * 32];
  __shared__ __align__(16) u16 sW[128 * 32];
  const int tid = threadIdx.x;
  const int lane = tid & 63, wid = tid >> 6;
  const int m0 = blockIdx.x * 128, n0 = blockIdx.y * 128;
  const int fr = lane & 15, fq = lane >> 4;
  const int wr = wid >> 1, wc = wid & 1;

  f32x4 acc[4][4] = {};

  const int r0 = tid >> 2, kc0 = tid & 3;
  const int t1 = tid + 256;
  const int r1 = t1 >> 2, kc1 = t1 & 3;
  const u16* gA0 = A + (m0 + r0) * 768 + kc0 * 8;
  const u16* gA1 = A + (m0 + r1) * 768 + kc1 * 8;
  const u16* gW0 = W + (n0 + r0) * 768 + kc0 * 8;
  const u16* gW1 = W + (n0 + r1) * 768 + kc1 * 8;
  u16* lA0 = sA + (wid * 64) * 8;
  u16* lA1 = sA + (256 + wid * 64) * 8;
  u16* lW0 = sW + (wid * 64) * 8;
  u16* lW1 = sW + (256 + wid * 64) * 8;

  const u16* pa = sA + (wr * 64 + fr) * 32 + fq * 8;
  const u16* pb = sW + (wc * 64 + fr) * 32 + fq * 8;

  for (int k0 = 0; k0 < 768; k0 += 32) {
    __syncthreads();
    gld_lds16(gA0 + k0, lA0);
    gld_lds16(gA1 + k0, lA1);
    gld_lds16(gW0 + k0, lW0);
    gld_lds16(gW1 + k0, lW1);
    __syncthreads();
    bf16x8 a[4], b[4];
#pragma unroll
    for (int i = 0; i < 4; i++) a[i] = *(const bf16x8*)(pa + i * 16 * 32);
#pragma unroll
    for (int j = 0; j < 4; j++) b[j] = *(const bf16x8*)(pb + j * 16 * 32);
#pragma unroll
    for (int i = 0; i < 4; i++)
#pragma unroll
      for (int j = 0; j < 4; j++)
        acc[i][j] = __builtin_amdgcn_mfma_f32_16x16x32_bf16(a[i], b[j], acc[i][j], 0, 0, 0);
  }

  if (MODE == 2) {
#pragma unroll
    for (int j = 0; j < 4; j++) {
      int n = n0 + wc * 64 + j * 16 + fr;
      float bj = bias0[n];
#pragma unroll
      for (int i = 0; i < 4; i++) {
#pragma unroll
        for (int r = 0; r < 4; r++) {
          int m = m0 + wr * 64 + i * 16 + fq * 4 + r;
          if (m < Mrows) of[(u64)m * 768 + n] = acc[i][j][r] + bj;
        }
      }
    }
  } else {
#pragma unroll
    for (int j = 0; j < 4; j++) {
      int n = n0 + wc * 64 + j * 16 + fr;
      u16* dst; float bj; int nn;
      if (MODE == 1 && n >= 768) { nn = n - 768; dst = o1; bj = bias1[nn]; }
      else { nn = n; dst = o0; bj = bias0[nn]; }
      int h = nn / 96, d = nn - h * 96;
#pragma unroll
      for (int i = 0; i < 4; i++) {
#pragma unroll
        for (int r = 0; r < 4; r++) {
          int m = m0 + wr * 64 + i * 16 + fq * 4 + r;
          if (m < Mrows) {
            int bidx = m / 511, l = m - bidx * 511;
            dst[((bidx * 8 + h) * 512 + l) * 96 + d] = f2b(acc[i][j][r] + bj);
          }
        }
      }
    }
  }
}

// ---- flash attention: 1 block = (b, h, 64 q rows), 4 waves x 16 rows, KV tiles of 32
#define VPAD 56
__global__ __launch_bounds__(256) void attn_kernel(
    const u16* __restrict__ Q, const u16* __restrict__ K, const u16* __restrict__ V,
    u16* __restrict__ ctxb)
{
  __shared__ __align__(16) u16 sK[32 * 96];
  __shared__ __align__(16) u16 sV[96 * VPAD];
  __shared__ __align__(16) u16 sP[4][16 * 32];
  const int tid = threadIdx.x, lane = tid & 63, wid = tid >> 6;
  const int b = blockIdx.z, h = blockIdx.y, q0 = blockIdx.x * 64;
  const int fr = lane & 15, fq = lane >> 4;
  const int hb = (b * NHEAD + h) * 512 * 96;

  int qr = q0 + wid * 16 + fr; if (qr > 510) qr = 510;
  bf16x8 qf[3];
#pragma unroll
  for (int ks = 0; ks < 3; ks++)
    qf[ks] = *(const bf16x8*)(Q + hb + qr * 96 + ks * 32 + fq * 8);

  f32x4 ctx[6] = {};
  float mrow[4], lrow[4];
#pragma unroll
  for (int r = 0; r < 4; r++) { mrow[r] = -1e30f; lrow[r] = 0.f; }
  const float scale = 0.10206207261596575f; // 1/sqrt(96)

  const int vkv = tid >> 3, vjj = tid & 7;

  for (int kv0 = 0; kv0 < Ll; kv0 += 32) {
    __syncthreads();
    { // K tile, linear [32][96] via global_load_lds (384 chunks of 16B)
      int c = tid;
      int krow = c / 12, kc = c - krow * 12;
      int kv = kv0 + krow; if (kv > 510) kv = 510;
      gld_lds16(K + hb + kv * 96 + kc * 8, sK + (wid * 64) * 8);
      if (wid < 2) {
        int c2 = tid + 256;
        int krow2 = c2 / 12, kc2 = c2 - krow2 * 12;
        int kv2 = kv0 + krow2; if (kv2 > 510) kv2 = 510;
        gld_lds16(K + hb + kv2 * 96 + kc2 * 8, sK + (256 + wid * 64) * 8);
      }
    }
    { // V tile transposed -> sV[d][kv]
      int kvv = kv0 + vkv; if (kvv > 510) kvv = 510;
      const u16* vrow = V + hb + kvv * 96;
#pragma unroll
      for (int i = 0; i < 6; i++) {
        int d2 = vjj + i * 8;
        u32 val = *(const u32*)(vrow + d2 * 2);
        sV[(2 * d2) * VPAD + vkv] = (u16)(val & 0xffffu);
        sV[(2 * d2 + 1) * VPAD + vkv] = (u16)(val >> 16);
      }
    }
    __syncthreads();

    // S = Q K^T
    f32x4 s0 = {}, s1 = {};
#pragma unroll
    for (int ks = 0; ks < 3; ks++) {
      bf16x8 kf0 = *(const bf16x8*)(sK + fr * 96 + ks * 32 + fq * 8);
      bf16x8 kf1 = *(const bf16x8*)(sK + (16 + fr) * 96 + ks * 32 + fq * 8);
      s0 = __builtin_amdgcn_mfma_f32_16x16x32_bf16(qf[ks], kf0, s0, 0, 0, 0);
      s1 = __builtin_amdgcn_mfma_f32_16x16x32_bf16(qf[ks], kf1, s1, 0, 0, 0);
    }
    const bool v0ok = (kv0 + fr) < Ll;
    const bool v1ok = (kv0 + 16 + fr) < Ll;
    float p0[4], p1[4], fac[4];
#pragma unroll
    for (int r = 0; r < 4; r++) {
      float x0 = v0ok ? s0[r] * scale : -1e30f;
      float x1 = v1ok ? s1[r] * scale : -1e30f;
      float rm = fmaxf(x0, x1);
#pragma unroll
      for (int off = 1; off < 16; off <<= 1) rm = fmaxf(rm, __shfl_xor(rm, off, 64));
      float mn = fmaxf(mrow[r], rm);
      fac[r] = __expf(mrow[r] - mn);
      mrow[r] = mn;
      p0[r] = __expf(x0 - mn);
      p1[r] = __expf(x1 - mn);
      float rs = p0[r] + p1[r];
#pragma unroll
      for (int off = 1; off < 16; off <<= 1) rs += __shfl_xor(rs, off, 64);
      lrow[r] = lrow[r] * fac[r] + rs;
    }
#pragma unroll
    for (int df = 0; df < 6; df++)
#pragma unroll
      for (int r = 0; r < 4; r++) ctx[df][r] *= fac[r];

    // P -> LDS (per-wave), read back as A-fragment
    u16* pw = &sP[wid][0];
#pragma unroll
    for (int r = 0; r < 4; r++) {
      pw[(fq * 4 + r) * 32 + fr] = f2b(p0[r]);
      pw[(fq * 4 + r) * 32 + 16 + fr] = f2b(p1[r]);
    }
    bf16x8 pf = *(const bf16x8*)(pw + fr * 32 + fq * 8);
#pragma unroll
    for (int df = 0; df < 6; df++) {
      bf16x8 vf = *(const bf16x8*)(sV + (df * 16 + fr) * VPAD + fq * 8);
      ctx[df] = __builtin_amdgcn_mfma_f32_16x16x32_bf16(pf, vf, ctx[df], 0, 0, 0);
    }
  }

#pragma unroll
  for (int df = 0; df < 6; df++) {
#pragma unroll
    for (int r = 0; r < 4; r++) {
      int q = q0 + wid * 16 + fq * 4 + r;
      if (q < Ll) {
        float o = ctx[df][r] / lrow[r];
        ctxb[(b * Ll + q) * 768 + h * 96 + df * 16 + fr] = f2b(o);
      }
    }
  }
}

// ---- per-channel sums over rows (axis (0,2) of (B,H,L))
__global__ __launch_bounds__(256) void stats_kernel(const float* __restrict__ ao,
                                                    float* __restrict__ ssum, float* __restrict__ ssq)
{
  int t = threadIdx.x;
  int row0 = blockIdx.x * 128;
  int rowEnd = row0 + 128; if (rowEnd > Mrows) rowEnd = Mrows;
  float s[3] = {0.f, 0.f, 0.f}, q[3] = {0.f, 0.f, 0.f};
  for (int m = row0; m < rowEnd; m++) {
    const float* rp = ao + (u64)m * 768;
#pragma unroll
    for (int i = 0; i < 3; i++) {
      float v = rp[t + i * 256];
      s[i] += v; q[i] += v * v;
    }
  }
#pragma unroll
  for (int i = 0; i < 3; i++) {
    atomicAdd(&ssum[t + i * 256], s[i]);
    atomicAdd(&ssq[t + i * 256], q[i]);
  }
}

__global__ __launch_bounds__(256) void derived_kernel(
    const float* __restrict__ ssum, const float* __restrict__ ssq,
    const float* __restrict__ w_out, const float* __restrict__ b_out,
    const float* __restrict__ gamma, const float* __restrict__ beta,
    float* __restrict__ weff, float* __restrict__ consts)
{
  __shared__ float red[256];
  int t = threadIdx.x;
  float acc = 0.f;
  const float invN = 1.f / 32704.f;
#pragma unroll
  for (int i = 0; i < 3; i++) {
    int hh = t + i * 256;
    float mu = ssum[hh] * invN;
    float var = ssq[hh] * invN - mu * mu;
    float rstd = 1.f / sqrtf(var + 1e-5f);
    float we = w_out[hh] * gamma[hh] * rstd;
    weff[hh] = we;
    acc += w_out[hh] * beta[hh] - we * mu;
  }
  red[t] = acc; __syncthreads();
  for (int s = 128; s > 0; s >>= 1) { if (t < s) red[t] += red[t + s]; __syncthreads(); }
  if (t == 0) consts[0] = b_out[0] + red[0];
}

// ---- fv[m] = dot(c_row, w_out) + dot(a_row, weff) + const   (one wave per row)
__global__ __launch_bounds__(256) void fv_kernel(
    const float* __restrict__ ao, const float* __restrict__ cols,
    const float* __restrict__ w_out, const float* __restrict__ weff,
    const float* __restrict__ consts, float* __restrict__ fv)
{
  int lane = threadIdx.x & 63, wid = threadIdx.x >> 6;
  int m = blockIdx.x * 4 + wid;
  if (m >= Mrows) return;
  int bidx = m / 511, l = m - bidx * 511;
  const float* ap = ao + (u64)m * 768;
  const float* cp = cols + (u64)(bidx * 512 + l + 1) * 768;
  float acc = 0.f;
#pragma unroll
  for (int i = 0; i < 12; i++) {
    int hh = lane + i * 64;
    acc += ap[hh] * weff[hh] + cp[hh] * w_out[hh];
  }
#pragma unroll
  for (int off = 1; off < 64; off <<= 1) acc += __shfl_xor(acc, off, 64);
  if (lane == 0) fv[m] = acc + consts[0];
}

// ---- comma-delimited segment means, one wave per batch row
__global__ __launch_bounds__(64) void seg_kernel(
    const float* __restrict__ fv, const int* __restrict__ ids, float* __restrict__ out)
{
  __shared__ float ssum[NSEG];
  __shared__ int scnt[NSEG];
  int lane = threadIdx.x;
  int b = blockIdx.x;
  if (lane < NSEG) { ssum[lane] = 0.f; scnt[lane] = 0; }
  __syncthreads();
  int carry = 0;
  for (int it = 0; it < 8; it++) {
    int l = it * 64 + lane;
    bool active = l < Ll;
    int id = active ? ids[b * 512 + l] : 0;
    bool comma = active && (id == COMMA_IDC);
    u64 cmask = __ballot(comma);
    int seg = carry + __popcll(cmask & ((1ull << lane) - 1ull));
    bool valid = active && (l >= 1) && !comma;
    if (valid && seg < NSEG) {
      atomicAdd(&ssum[seg], fv[b * Ll + l]);
      atomicAdd(&scnt[seg], 1);
    }
    carry += __popcll(cmask);
  }
  __syncthreads();
  if (lane < NSEG) {
    float c = (float)scnt[lane];
    out[b * NSEG + lane] = ssum[lane] / fmaxf(c, 1.f);
  }
}

extern "C" void kernel_launch(void* const* d_in, const int* in_sizes, int n_in,
                              void* d_out, int out_size, void* d_ws, size_t ws_size,
                              hipStream_t stream)
{
  const float* text  = (const float*)d_in[0];
  const float* cols  = (const float*)d_in[1];
  const float* wq    = (const float*)d_in[2];
  const float* wk    = (const float*)d_in[3];
  const float* wvp   = (const float*)d_in[4];
  const float* bq    = (const float*)d_in[5];
  const float* bk    = (const float*)d_in[6];
  const float* bv    = (const float*)d_in[7];
  const float* wo    = (const float*)d_in[8];
  const float* bo    = (const float*)d_in[9];
  const float* gamma = (const float*)d_in[10];
  const float* beta  = (const float*)d_in[11];
  const float* w_out = (const float*)d_in[12];
  const float* b_out = (const float*)d_in[13];
  const int*   ids   = (const int*)d_in[14];
  float* out = (float*)d_out;

  char* ws = (char*)d_ws;
  u16* cb    = (u16*)(ws + 0ull);             // [MPAD][768] bf16
  u16* tb    = (u16*)(ws + 50331648ull);      // [MPAD][768] bf16
  u16* wqkvb = (u16*)(ws + 100663296ull);     // [2304][768] bf16
  u16* wob   = (u16*)(ws + 104202240ull);     // [768][768] bf16
  u16* Qb    = (u16*)(ws + 105381888ull);     // [64][8][512][96] bf16
  u16* Kb    = (u16*)(ws + 155713536ull);
  u16* Vb    = (u16*)(ws + 206045184ull);
  u16* ctxb  = (u16*)(ws + 256376832ull);     // [MPAD][768] bf16
  float* ao  = (float*)(ws + 0ull);           // [MPAD][768] f32, aliases cb+tb (dead after GEMM1)
  float* ssum   = (float*)(ws + 105381888ull); // aliases Qb (dead after attn)
  float* ssq    = ssum + 768;
  float* weff   = ssum + 1536;
  float* consts = ssum + 2304;
  float* fv     = (float*)(ws + 105381888ull + 16384ull);

  conv_sliced<<<dim3(384, 64), 256, 0, stream>>>((const float4*)cols, (ushort4*)cb);
  conv_sliced<<<dim3(384, 64), 256, 0, stream>>>((const float4*)text, (ushort4*)tb);
  conv_flat<<<576, 256, 0, stream>>>((const float4*)wq, (ushort4*)wqkvb, 147456);
  conv_flat<<<576, 256, 0, stream>>>((const float4*)wk, (ushort4*)(wqkvb + 589824), 147456);
  conv_flat<<<576, 256, 0, stream>>>((const float4*)wvp, (ushort4*)(wqkvb + 1179648), 147456);
  conv_flat<<<576, 256, 0, stream>>>((const float4*)wo, (ushort4*)wob, 147456);

  gemm128<0><<<dim3(256, 6), 256, 0, stream>>>(cb, wqkvb, bq, nullptr, Qb, nullptr, nullptr);
  gemm128<1><<<dim3(256, 12), 256, 0, stream>>>(tb, wqkvb + 589824, bk, bv, Kb, Vb, nullptr);
  attn_kernel<<<dim3(8, 8, 64), 256, 0, stream>>>(Qb, Kb, Vb, ctxb);
  gemm128<2><<<dim3(256, 6), 256, 0, stream>>>(ctxb, wob, bo, nullptr, nullptr, nullptr, ao);

  zero_kernel<<<6, 256, 0, stream>>>(ssum, 1536);
  stats_kernel<<<256, 256, 0, stream>>>(ao, ssum, ssq);
  derived_kernel<<<1, 256, 0, stream>>>(ssum, ssq, w_out, b_out, gamma, beta, weff, consts);
  fv_kernel<<<8176, 256, 0, stream>>>(ao, cols, w_out, weff, consts, fv);
  seg_kernel<<<64, 64, 0, stream>>>(fv, ids, out);
}

// Round 2
// 529.700 us; speedup vs baseline: 1.1750x; 1.1750x over previous
//
#include <hip/hip_runtime.h>
#include <hip/hip_bf16.h>

#define COMMA_IDC 1010
#define NHEAD 8
#define Ll 511
#define Mrows 32704
#define NSEG 17

typedef __attribute__((ext_vector_type(8))) short bf16x8;
typedef __attribute__((ext_vector_type(4))) float f32x4;
typedef unsigned short u16;
typedef unsigned int u32;
typedef unsigned long long u64;

__device__ __forceinline__ u16 f2b(float f) {
  __hip_bfloat16 h = __float2bfloat16(f);
  return *reinterpret_cast<u16*>(&h);
}
__device__ __forceinline__ float b2f(u16 u) {
  u32 x = ((u32)u) << 16;
  return __builtin_bit_cast(float, x);
}

__device__ __forceinline__ void gld_lds16(const void* g, void* l) {
  __builtin_amdgcn_global_load_lds(
      (const __attribute__((address_space(1))) void*)(u64)g,
      (__attribute__((address_space(3))) void*)(u32)(u64)l,
      16, 0, 0);
}

#define MFMA16(a, b, c) __builtin_amdgcn_mfma_f32_16x16x32_bf16(a, b, c, 0, 0, 0)

// ---- convert f32 -> bf16, slicing off token 0 : rows m=b*511+l from (b, l+1)
__global__ void conv_sliced(const float4* __restrict__ src, ushort4* __restrict__ dst) {
  int b = blockIdx.y;
  int idx = blockIdx.x * 256 + threadIdx.x;
  if (idx >= Ll * 192) return;
  int l = idx / 192, c = idx - l * 192;
  float4 v = src[(b * 512 + l + 1) * 192 + c];
  ushort4 o; o.x = f2b(v.x); o.y = f2b(v.y); o.z = f2b(v.z); o.w = f2b(v.w);
  dst[(b * Ll + l) * 192 + c] = o;
}

__global__ void conv_flat(const float4* __restrict__ src, ushort4* __restrict__ dst, int n4) {
  int i = blockIdx.x * 256 + threadIdx.x;
  if (i < n4) {
    float4 v = src[i];
    ushort4 o; o.x = f2b(v.x); o.y = f2b(v.y); o.z = f2b(v.z); o.w = f2b(v.w);
    dst[i] = o;
  }
}

__global__ void zero_kernel(float* p, int n) {
  int i = blockIdx.x * 256 + threadIdx.x;
  if (i < n) p[i] = 0.f;
}

// ---- 128x128x(K=768) bf16 MFMA GEMM, C = A @ W^T + bias.  W is [N][768] row-major.
// 1-D grid, XCD-owned m-rows: xcd = fid&7 owns m-tiles [xcd*32, xcd*32+32), n fastest.
// MODE 0: out bf16 -> Q layout [b][h][512][96]
// MODE 1: out bf16 -> K (n<768) / V (n>=768) layouts [b][h][512][96]
// MODE 2: out bf16 -> o0[m*768+n]
template<int MODE, int NT>
__global__ __launch_bounds__(256) void gemm128(
    const u16* __restrict__ A, const u16* __restrict__ W,
    const float* __restrict__ bias0, const float* __restrict__ bias1,
    u16* __restrict__ o0, u16* __restrict__ o1)
{
  __shared__ __align__(16) u16 sA[128 * 32];
  __shared__ __align__(16) u16 sW[128 * 32];
  const int tid = threadIdx.x;
  const int lane = tid & 63, wid = tid >> 6;
  int fid = blockIdx.x;
  int xcd = fid & 7, t = fid >> 3;
  int mrow = xcd * 32 + t / NT;
  int ncol = t - (t / NT) * NT;
  const int m0 = mrow * 128, n0 = ncol * 128;
  const int fr = lane & 15, fq = lane >> 4;
  const int wr = wid >> 1, wc = wid & 1;

  f32x4 acc[4][4] = {};

  const int r0 = tid >> 2, kc0 = tid & 3;
  const int t1 = tid + 256;
  const int r1 = t1 >> 2, kc1 = t1 & 3;
  const u16* gA0 = A + (m0 + r0) * 768 + kc0 * 8;
  const u16* gA1 = A + (m0 + r1) * 768 + kc1 * 8;
  const u16* gW0 = W + (n0 + r0) * 768 + kc0 * 8;
  const u16* gW1 = W + (n0 + r1) * 768 + kc1 * 8;
  u16* lA0 = sA + (wid * 64) * 8;
  u16* lA1 = sA + (256 + wid * 64) * 8;
  u16* lW0 = sW + (wid * 64) * 8;
  u16* lW1 = sW + (256 + wid * 64) * 8;

  const u16* pa = sA + (wr * 64 + fr) * 32 + fq * 8;
  const u16* pb = sW + (wc * 64 + fr) * 32 + fq * 8;

  for (int k0 = 0; k0 < 768; k0 += 32) {
    __syncthreads();
    gld_lds16(gA0 + k0, lA0);
    gld_lds16(gA1 + k0, lA1);
    gld_lds16(gW0 + k0, lW0);
    gld_lds16(gW1 + k0, lW1);
    __syncthreads();
    bf16x8 a[4], b[4];
#pragma unroll
    for (int i = 0; i < 4; i++) a[i] = *(const bf16x8*)(pa + i * 16 * 32);
#pragma unroll
    for (int j = 0; j < 4; j++) b[j] = *(const bf16x8*)(pb + j * 16 * 32);
#pragma unroll
    for (int i = 0; i < 4; i++)
#pragma unroll
      for (int j = 0; j < 4; j++)
        acc[i][j] = MFMA16(a[i], b[j], acc[i][j]);
  }

  if (MODE == 2) {
#pragma unroll
    for (int j = 0; j < 4; j++) {
      int n = n0 + wc * 64 + j * 16 + fr;
      float bj = bias0[n];
#pragma unroll
      for (int i = 0; i < 4; i++) {
#pragma unroll
        for (int r = 0; r < 4; r++) {
          int m = m0 + wr * 64 + i * 16 + fq * 4 + r;
          if (m < Mrows) o0[(u64)m * 768 + n] = f2b(acc[i][j][r] + bj);
        }
      }
    }
  } else {
#pragma unroll
    for (int j = 0; j < 4; j++) {
      int n = n0 + wc * 64 + j * 16 + fr;
      u16* dst; float bj; int nn;
      if (MODE == 1 && n >= 768) { nn = n - 768; dst = o1; bj = bias1[nn]; }
      else { nn = n; dst = o0; bj = bias0[nn]; }
      int h = nn / 96, d = nn - h * 96;
#pragma unroll
      for (int i = 0; i < 4; i++) {
#pragma unroll
        for (int r = 0; r < 4; r++) {
          int m = m0 + wr * 64 + i * 16 + fq * 4 + r;
          if (m < Mrows) {
            int bidx = m / 511, l = m - bidx * 511;
            dst[((bidx * 8 + h) * 512 + l) * 96 + d] = f2b(acc[i][j][r] + bj);
          }
        }
      }
    }
  }
}

// ---- V transpose: [b,h,512,96] -> [b,h,96,512], XOR-swizzled LDS tile
__global__ __launch_bounds__(256) void vtrans(const u16* __restrict__ V, u16* __restrict__ VT) {
  __shared__ __align__(16) u16 sT[128 * 128];
  int bh = blockIdx.y;
  int l0 = blockIdx.x * 128;
  const u16* in = V + (u64)bh * 512 * 96;
  u16* outp = VT + (u64)bh * 96 * 512;
  int t = threadIdx.x;
#pragma unroll
  for (int k = 0; k < 6; k++) {
    int c = t + k * 256;
    int l = c / 12, ch = c - l * 12;
    bf16x8 v = *(const bf16x8*)(in + (u64)(l0 + l) * 96 + ch * 8);
    int chunk = l * 16 + (ch ^ ((l >> 3) & 7));
    *(bf16x8*)(sT + chunk * 8) = v;
  }
  __syncthreads();
#pragma unroll
  for (int k = 0; k < 6; k++) {
    int c = t + k * 256;
    int d = c >> 4, lch = c & 15;
    u16 vals[8];
#pragma unroll
    for (int k2 = 0; k2 < 8; k2++) {
      int r = lch * 8 + k2;
      int idx = r * 128 + (((d >> 3) ^ (lch & 7)) << 3) + (d & 7);
      vals[k2] = sT[idx];
    }
    bf16x8 o;
#pragma unroll
    for (int k2 = 0; k2 < 8; k2++) o[k2] = (short)vals[k2];
    *(bf16x8*)(outp + (u64)d * 512 + l0 + lch * 8) = o;
  }
}

// ---- flash attention, fixed-max softmax. Block = 128 q rows, 4 waves x 32 q.
// K: [b,h,512,96]  VT: [b,h,96,512] (staged with inverse-swizzled source).
#define PST 36
__global__ __launch_bounds__(256) void attn_kernel(
    const u16* __restrict__ Q, const u16* __restrict__ K, const u16* __restrict__ VT,
    u16* __restrict__ ctxb)
{
  __shared__ __align__(16) u16 sK[32 * 96];
  __shared__ __align__(16) u16 sV[32 * 96];
  __shared__ __align__(16) u16 sP[4][16 * PST];
  const int tid = threadIdx.x, lane = tid & 63, wid = tid >> 6;
  // XCD-grouped decode: 4 q-slots of one (b,h) share an XCD
  int fid = blockIdx.x;
  int xcd = fid & 7, slot = (fid >> 3) & 3, grp = fid >> 5;
  int bh = grp * 8 + xcd;
  int b = bh >> 3, h = bh & 7;
  int q0 = slot * 128;
  const int fr = lane & 15, fq = lane >> 4;
  const u64 hbK = (u64)bh * 512 * 96;
  const u64 hbV = (u64)bh * 96 * 512;

  // Q fragments: 2 subtiles x 3 k-slices
  bf16x8 qf[2][3];
#pragma unroll
  for (int sub = 0; sub < 2; sub++) {
    int qr = q0 + wid * 32 + sub * 16 + fr; if (qr > 510) qr = 510;
#pragma unroll
    for (int ks = 0; ks < 3; ks++)
      qf[sub][ks] = *(const bf16x8*)(Q + hbK + (u64)qr * 96 + ks * 32 + fq * 8);
  }

  f32x4 ctx[2][6] = {};
  f32x4 sumP[2] = {};

  // staging: K chunks c = wid*64+lane (+256 for wid<2); V same (+256 for wid>=2)
  int cK1 = wid * 64 + lane;
  int kr1 = cK1 / 12, kc1 = cK1 - kr1 * 12;
  const u16* gK1 = K + hbK + (u64)kr1 * 96 + kc1 * 8;
  int cK2 = 256 + cK1;
  int kr2 = cK2 / 12, kc2 = cK2 - kr2 * 12;
  const u16* gK2 = K + hbK + (u64)kr2 * 96 + kc2 * 8;
  int cV1 = wid * 64 + lane;
  int dV1 = cV1 >> 2, jV1 = (cV1 & 3) ^ ((dV1 >> 1) & 3);
  const u16* gV1 = VT + hbV + (u64)dV1 * 512 + jV1 * 8;
  int cV2 = 256 + (wid - 2) * 64 + lane;
  int dV2 = cV2 >> 2, jV2 = (cV2 & 3) ^ ((dV2 >> 1) & 3);
  const u16* gV2 = VT + hbV + (u64)dV2 * 512 + jV2 * 8;

  u16* lK1 = sK + (u32)(wid * 64) * 8;
  u16* lK2 = sK + (u32)(256 + wid * 64) * 8;
  u16* lV1 = sV + (u32)(wid * 64) * 8;
  u16* lV2 = sV + (u32)(256 + (wid - 2) * 64) * 8;
  u16* pw = &sP[wid][0];

  const float cs = 0.10206207261596575f; // 1/sqrt(96)
  const int cpx = fq ^ ((fr >> 1) & 3);  // V read swizzle (d-dependent, df-invariant)

  for (int kv0 = 0; kv0 < 511; kv0 += 32) {
    __syncthreads();
    gld_lds16(gK1, lK1); gK1 += 32 * 96;
    if (wid < 2) { gld_lds16(gK2, lK2); gK2 += 32 * 96; }
    gld_lds16(gV1, lV1); gV1 += 32;
    if (wid >= 2) { gld_lds16(gV2, lV2); gV2 += 32; }
    __syncthreads();

    bf16x8 kf0[3], kf1[3];
#pragma unroll
    for (int ks = 0; ks < 3; ks++) {
      kf0[ks] = *(const bf16x8*)(sK + fr * 96 + ks * 32 + fq * 8);
      kf1[ks] = *(const bf16x8*)(sK + (16 + fr) * 96 + ks * 32 + fq * 8);
    }
    const bool ok1 = (kv0 + 16 + fr) < Ll;

#pragma unroll
    for (int sub = 0; sub < 2; sub++) {
      f32x4 s0 = {}, s1 = {};
#pragma unroll
      for (int ks = 0; ks < 3; ks++) {
        s0 = MFMA16(qf[sub][ks], kf0[ks], s0);
        s1 = MFMA16(qf[sub][ks], kf1[ks], s1);
      }
      float p0[4], p1[4];
#pragma unroll
      for (int r = 0; r < 4; r++) {
        p0[r] = __expf(s0[r] * cs);
        float e1 = __expf(s1[r] * cs);
        p1[r] = ok1 ? e1 : 0.f;
        sumP[sub][r] += p0[r] + p1[r];
      }
#pragma unroll
      for (int r = 0; r < 4; r++) {
        int row = fq * 4 + r;
        pw[row * PST + fr] = f2b(p0[r]);
        pw[row * PST + 16 + fr] = f2b(p1[r]);
      }
      bf16x8 pf = *(const bf16x8*)(pw + fr * PST + fq * 8);
#pragma unroll
      for (int df = 0; df < 6; df++) {
        bf16x8 vf = *(const bf16x8*)(sV + (df * 16 + fr) * 32 + cpx * 8);
        ctx[sub][df] = MFMA16(pf, vf, ctx[sub][df]);
      }
    }
  }

#pragma unroll
  for (int sub = 0; sub < 2; sub++) {
    float inv[4];
#pragma unroll
    for (int r = 0; r < 4; r++) {
      float s = sumP[sub][r];
      s += __shfl_xor(s, 1, 64);
      s += __shfl_xor(s, 2, 64);
      s += __shfl_xor(s, 4, 64);
      s += __shfl_xor(s, 8, 64);
      inv[r] = 1.f / s;
    }
#pragma unroll
    for (int df = 0; df < 6; df++) {
#pragma unroll
      for (int r = 0; r < 4; r++) {
        int q = q0 + wid * 32 + sub * 16 + fq * 4 + r;
        if (q < Ll)
          ctxb[(u64)(b * Ll + q) * 768 + h * 96 + df * 16 + fr] = f2b(ctx[sub][df][r] * inv[r]);
      }
    }
  }
}

// ---- per-channel sums over rows (bf16 input)
__global__ __launch_bounds__(256) void stats_kernel(const u16* __restrict__ ao,
                                                    float* __restrict__ ssum, float* __restrict__ ssq)
{
  int t = threadIdx.x;
  int row0 = blockIdx.x * 128;
  int rowEnd = row0 + 128; if (rowEnd > Mrows) rowEnd = Mrows;
  float s[3] = {0.f, 0.f, 0.f}, q[3] = {0.f, 0.f, 0.f};
  for (int m = row0; m < rowEnd; m++) {
    const u16* rp = ao + (u64)m * 768;
#pragma unroll
    for (int i = 0; i < 3; i++) {
      float v = b2f(rp[t + i * 256]);
      s[i] += v; q[i] += v * v;
    }
  }
#pragma unroll
  for (int i = 0; i < 3; i++) {
    atomicAdd(&ssum[t + i * 256], s[i]);
    atomicAdd(&ssq[t + i * 256], q[i]);
  }
}

__global__ __launch_bounds__(256) void derived_kernel(
    const float* __restrict__ ssum, const float* __restrict__ ssq,
    const float* __restrict__ w_out, const float* __restrict__ b_out,
    const float* __restrict__ gamma, const float* __restrict__ beta,
    float* __restrict__ weff, float* __restrict__ consts)
{
  __shared__ float red[256];
  int t = threadIdx.x;
  float acc = 0.f;
  const float invN = 1.f / 32704.f;
#pragma unroll
  for (int i = 0; i < 3; i++) {
    int hh = t + i * 256;
    float mu = ssum[hh] * invN;
    float var = ssq[hh] * invN - mu * mu;
    float rstd = 1.f / sqrtf(var + 1e-5f);
    float we = w_out[hh] * gamma[hh] * rstd;
    weff[hh] = we;
    acc += w_out[hh] * beta[hh] - we * mu;
  }
  red[t] = acc; __syncthreads();
  for (int s = 128; s > 0; s >>= 1) { if (t < s) red[t] += red[t + s]; __syncthreads(); }
  if (t == 0) consts[0] = b_out[0] + red[0];
}

// ---- fv[m] = dot(c_row, w_out) + dot(a_row, weff) + const   (one wave per row)
__global__ __launch_bounds__(256) void fv_kernel(
    const u16* __restrict__ ao, const u16* __restrict__ cb,
    const float* __restrict__ w_out, const float* __restrict__ weff,
    const float* __restrict__ consts, float* __restrict__ fv)
{
  int lane = threadIdx.x & 63, wid = threadIdx.x >> 6;
  int m = blockIdx.x * 4 + wid;
  if (m >= Mrows) return;
  const u16* ap = ao + (u64)m * 768;
  const u16* cp = cb + (u64)m * 768;
  float acc = 0.f;
#pragma unroll
  for (int i = 0; i < 12; i++) {
    int hh = lane + i * 64;
    acc += b2f(ap[hh]) * weff[hh] + b2f(cp[hh]) * w_out[hh];
  }
#pragma unroll
  for (int off = 1; off < 64; off <<= 1) acc += __shfl_xor(acc, off, 64);
  if (lane == 0) fv[m] = acc + consts[0];
}

// ---- comma-delimited segment means, one wave per batch row
__global__ __launch_bounds__(64) void seg_kernel(
    const float* __restrict__ fv, const int* __restrict__ ids, float* __restrict__ out)
{
  __shared__ float ssum[NSEG];
  __shared__ int scnt[NSEG];
  int lane = threadIdx.x;
  int b = blockIdx.x;
  if (lane < NSEG) { ssum[lane] = 0.f; scnt[lane] = 0; }
  __syncthreads();
  int carry = 0;
  for (int it = 0; it < 8; it++) {
    int l = it * 64 + lane;
    bool active = l < Ll;
    int id = active ? ids[b * 512 + l] : 0;
    bool comma = active && (id == COMMA_IDC);
    u64 cmask = __ballot(comma);
    int seg = carry + __popcll(cmask & ((1ull << lane) - 1ull));
    bool valid = active && (l >= 1) && !comma;
    if (valid && seg < NSEG) {
      atomicAdd(&ssum[seg], fv[b * Ll + l]);
      atomicAdd(&scnt[seg], 1);
    }
    carry += __popcll(cmask);
  }
  __syncthreads();
  if (lane < NSEG) {
    float c = (float)scnt[lane];
    out[b * NSEG + lane] = ssum[lane] / fmaxf(c, 1.f);
  }
}

extern "C" void kernel_launch(void* const* d_in, const int* in_sizes, int n_in,
                              void* d_out, int out_size, void* d_ws, size_t ws_size,
                              hipStream_t stream)
{
  const float* text  = (const float*)d_in[0];
  const float* cols  = (const float*)d_in[1];
  const float* wq    = (const float*)d_in[2];
  const float* wk    = (const float*)d_in[3];
  const float* wvp   = (const float*)d_in[4];
  const float* bq    = (const float*)d_in[5];
  const float* bk    = (const float*)d_in[6];
  const float* bv    = (const float*)d_in[7];
  const float* wo    = (const float*)d_in[8];
  const float* bo    = (const float*)d_in[9];
  const float* gamma = (const float*)d_in[10];
  const float* beta  = (const float*)d_in[11];
  const float* w_out = (const float*)d_in[12];
  const float* b_out = (const float*)d_in[13];
  const int*   ids   = (const int*)d_in[14];
  float* out = (float*)d_out;

  char* ws = (char*)d_ws;
  u16* cb    = (u16*)(ws + 0ull);             // [32768][768] bf16 (sliced cols), live till fv
  u16* tb    = (u16*)(ws + 50331648ull);      // [32768][768] bf16 -> ctxb reuses after gemm1
  u16* wqkvb = (u16*)(ws + 100663296ull);     // [2304][768] bf16
  u16* wob   = (u16*)(ws + 104202240ull);     // [768][768] bf16
  u16* Qb    = (u16*)(ws + 105381888ull);     // [64][8][512][96] -> aob reuses after attn
  u16* Kb    = (u16*)(ws + 155713536ull);     // -> stats area after attn
  u16* Vb    = (u16*)(ws + 206045184ull);     // dead after vtrans
  u16* VTb   = (u16*)(ws + 256376832ull);     // [64][8][96][512], live till attn done
  u16* ctxb  = tb;
  u16* aob   = Qb;
  float* ssum   = (float*)(ws + 155713536ull);
  float* ssq    = ssum + 768;
  float* weff   = ssum + 1536;
  float* consts = ssum + 2304;
  float* fv     = (float*)(ws + 155713536ull + 16384ull);

  conv_sliced<<<dim3(384, 64), 256, 0, stream>>>((const float4*)cols, (ushort4*)cb);
  conv_sliced<<<dim3(384, 64), 256, 0, stream>>>((const float4*)text, (ushort4*)tb);
  conv_flat<<<576, 256, 0, stream>>>((const float4*)wq, (ushort4*)wqkvb, 147456);
  conv_flat<<<576, 256, 0, stream>>>((const float4*)wk, (ushort4*)(wqkvb + 589824), 147456);
  conv_flat<<<576, 256, 0, stream>>>((const float4*)wvp, (ushort4*)(wqkvb + 1179648), 147456);
  conv_flat<<<576, 256, 0, stream>>>((const float4*)wo, (ushort4*)wob, 147456);

  gemm128<0, 6><<<1536, 256, 0, stream>>>(cb, wqkvb, bq, nullptr, Qb, nullptr);
  gemm128<1, 12><<<3072, 256, 0, stream>>>(tb, wqkvb + 589824, bk, bv, Kb, Vb);
  vtrans<<<dim3(4, 512), 256, 0, stream>>>(Vb, VTb);
  attn_kernel<<<2048, 256, 0, stream>>>(Qb, Kb, VTb, ctxb);

  zero_kernel<<<6, 256, 0, stream>>>(ssum, 1536);   // after attn: aliases Kb
  gemm128<2, 6><<<1536, 256, 0, stream>>>(ctxb, wob, bo, nullptr, aob, nullptr);
  stats_kernel<<<256, 256, 0, stream>>>(aob, ssum, ssq);
  derived_kernel<<<1, 256, 0, stream>>>(ssum, ssq, w_out, b_out, gamma, beta, weff, consts);
  fv_kernel<<<8176, 256, 0, stream>>>(aob, cb, w_out, weff, consts, fv);
  seg_kernel<<<64, 64, 0, stream>>>(fv, ids, out);
}

// Round 3
// 462.342 us; speedup vs baseline: 1.3462x; 1.1457x over previous
//
#include <hip/hip_runtime.h>
#include <hip/hip_bf16.h>

#define COMMA_IDC 1010
#define NHEAD 8
#define Ll 511
#define Mrows 32704
#define NSEG 17

typedef __attribute__((ext_vector_type(8))) short bf16x8;
typedef __attribute__((ext_vector_type(4))) float f32x4;
typedef unsigned short u16;
typedef unsigned int u32;
typedef unsigned long long u64;

__device__ __forceinline__ u16 f2b(float f) {
  __hip_bfloat16 h = __float2bfloat16(f);
  return *reinterpret_cast<u16*>(&h);
}
__device__ __forceinline__ float b2f(u16 u) {
  u32 x = ((u32)u) << 16;
  return __builtin_bit_cast(float, x);
}

__device__ __forceinline__ void gld_lds16(const void* g, void* l) {
  __builtin_amdgcn_global_load_lds(
      (const __attribute__((address_space(1))) void*)(u64)g,
      (__attribute__((address_space(3))) void*)(u32)(u64)l,
      16, 0, 0);
}

#define MFMA16(a, b, c) __builtin_amdgcn_mfma_f32_16x16x32_bf16(a, b, c, 0, 0, 0)

// ---- convert f32 -> bf16, slicing off token 0 : rows m=b*511+l from (b, l+1)
__global__ void conv_sliced(const float4* __restrict__ src, ushort4* __restrict__ dst) {
  int b = blockIdx.y;
  int idx = blockIdx.x * 256 + threadIdx.x;
  if (idx >= Ll * 192) return;
  int l = idx / 192, c = idx - l * 192;
  float4 v = src[(b * 512 + l + 1) * 192 + c];
  ushort4 o; o.x = f2b(v.x); o.y = f2b(v.y); o.z = f2b(v.z); o.w = f2b(v.w);
  dst[(b * Ll + l) * 192 + c] = o;
}

__global__ void conv_flat(const float4* __restrict__ src, ushort4* __restrict__ dst, int n4) {
  int i = blockIdx.x * 256 + threadIdx.x;
  if (i < n4) {
    float4 v = src[i];
    ushort4 o; o.x = f2b(v.x); o.y = f2b(v.y); o.z = f2b(v.z); o.w = f2b(v.w);
    dst[i] = o;
  }
}

__global__ void zero_kernel(float* p, int n) {
  int i = blockIdx.x * 256 + threadIdx.x;
  if (i < n) p[i] = 0.f;
}

// ---- 128x128x(K=768) bf16 MFMA GEMM, C = A @ W^T + bias, out [m][NOUT] bf16 row-major.
// Double-buffered LDS staging (prefetch-before-compute), LDS-staged coalesced epilogue.
// A = (ncol < QNT) ? A0 : A1.  Bias segment chosen per 768-col block: b0/b1/b2.
template<int NTILES, int NOUT, int QNT>
__global__ __launch_bounds__(256) void gemmk(
    const u16* __restrict__ A0, const u16* __restrict__ A1, const u16* __restrict__ W,
    const float* __restrict__ b0, const float* __restrict__ b1, const float* __restrict__ b2,
    u16* __restrict__ outp)
{
  __shared__ __align__(16) u16 sMem[16384];  // 32 KB: 2x(A dbuf 8KB) + 2x(W dbuf 8KB); epilogue reuses
  u16* sA = sMem;
  u16* sW = sMem + 8192;

  const int tid = threadIdx.x;
  const int lane = tid & 63, wid = tid >> 6;
  int fid = blockIdx.x;
  int xcd = fid & 7, t = fid >> 3;
  int mrow = xcd * 32 + t / NTILES;
  int ncol = t - (t / NTILES) * NTILES;
  const int m0 = mrow * 128, n0 = ncol * 128;
  const u16* __restrict__ A = (ncol < QNT) ? A0 : A1;
  const int fr = lane & 15, fq = lane >> 4;
  const int wr = wid >> 1, wc = wid & 1;

  f32x4 acc[4][4] = {};

  const int r0 = tid >> 2, kc0 = tid & 3;
  const u16* gA0 = A + (u64)(m0 + r0) * 768 + kc0 * 8;
  const u16* gA1 = A + (u64)(m0 + r0 + 64) * 768 + kc0 * 8;
  const u16* gW0 = W + (u64)(n0 + r0) * 768 + kc0 * 8;
  const u16* gW1 = W + (u64)(n0 + r0 + 64) * 768 + kc0 * 8;
  u16* lA0 = sA + wid * 512;
  u16* lA1 = sA + 2048 + wid * 512;
  u16* lW0 = sW + wid * 512;
  u16* lW1 = sW + 2048 + wid * 512;

  auto STAGE = [&](int buf, int kofs) {
    gld_lds16(gA0 + kofs, lA0 + buf * 4096);
    gld_lds16(gA1 + kofs, lA1 + buf * 4096);
    gld_lds16(gW0 + kofs, lW0 + buf * 4096);
    gld_lds16(gW1 + kofs, lW1 + buf * 4096);
  };
  auto COMPUTE = [&](int buf) {
    const u16* pa = sA + buf * 4096 + (wr * 64 + fr) * 32 + fq * 8;
    const u16* pb = sW + buf * 4096 + (wc * 64 + fr) * 32 + fq * 8;
    bf16x8 a[4], b[4];
#pragma unroll
    for (int i = 0; i < 4; i++) a[i] = *(const bf16x8*)(pa + i * 16 * 32);
#pragma unroll
    for (int j = 0; j < 4; j++) b[j] = *(const bf16x8*)(pb + j * 16 * 32);
#pragma unroll
    for (int i = 0; i < 4; i++)
#pragma unroll
      for (int j = 0; j < 4; j++)
        acc[i][j] = MFMA16(a[i], b[j], acc[i][j]);
  };

  STAGE(0, 0);
  for (int k0 = 0; k0 < 768; k0 += 64) {
    __syncthreads();                       // drains vmcnt: buf0 ready; all buf1 reads done
    if (k0 + 32 < 768) STAGE(1, k0 + 32);  // prefetch overlaps COMPUTE(0)
    COMPUTE(0);
    __syncthreads();
    if (k0 + 64 < 768) STAGE(0, k0 + 64);
    COMPUTE(1);
  }

  // bias for this block's 128-col slice (whole block lies in one 768-col segment)
  const int seg = n0 / 768, boff = n0 - seg * 768;
  const float* bp = (seg == 0) ? b0 : ((seg == 1) ? b1 : b2);
  float bj[4];
#pragma unroll
  for (int j = 0; j < 4; j++) bj[j] = bp[boff + wc * 64 + j * 16 + fr];

  // epilogue: acc -> LDS (stride 136) -> coalesced bf16x8 stores, 2 halves of 64 rows
#pragma unroll
  for (int half = 0; half < 2; half++) {
    __syncthreads();
#pragma unroll
    for (int i2 = 0; i2 < 2; i2++) {
      int i = half * 2 + i2;
#pragma unroll
      for (int j = 0; j < 4; j++) {
#pragma unroll
        for (int r = 0; r < 4; r++) {
          int lr = wr * 32 + i2 * 16 + fq * 4 + r;
          sMem[lr * 136 + wc * 64 + j * 16 + fr] = f2b(acc[i][j][r] + bj[j]);
        }
      }
    }
    __syncthreads();
#pragma unroll
    for (int c = 0; c < 4; c++) {
      int cc = tid + c * 256;
      int lr = cc >> 4, ch = cc & 15;
      int m = m0 + (lr >> 5) * 64 + half * 32 + (lr & 31);
      if (m < Mrows)
        *(bf16x8*)(outp + (u64)m * NOUT + n0 + ch * 8) =
            *(const bf16x8*)(sMem + lr * 136 + ch * 8);
    }
  }
}

// ---- V transpose: QKV[m][2304] V-cols -> VT [b,h,96,512], XOR-swizzled LDS tile
__global__ __launch_bounds__(256) void vtrans(const u16* __restrict__ QKV, u16* __restrict__ VT) {
  __shared__ __align__(16) u16 sT[128 * 128];
  int bh = blockIdx.y;
  int b = bh >> 3, h = bh & 7;
  int l0 = blockIdx.x * 128;
  u16* outp = VT + (u64)bh * 96 * 512;
  int t = threadIdx.x;
#pragma unroll
  for (int k = 0; k < 6; k++) {
    int c = t + k * 256;
    int l = c / 12, ch = c - l * 12;
    int lc = l0 + l; if (lc > 510) lc = 510;
    bf16x8 v = *(const bf16x8*)(QKV + (u64)(b * 511 + lc) * 2304 + 1536 + h * 96 + ch * 8);
    int chunk = l * 16 + (ch ^ ((l >> 3) & 7));
    *(bf16x8*)(sT + chunk * 8) = v;
  }
  __syncthreads();
#pragma unroll
  for (int k = 0; k < 6; k++) {
    int c = t + k * 256;
    int d = c >> 4, lch = c & 15;
    u16 vals[8];
#pragma unroll
    for (int k2 = 0; k2 < 8; k2++) {
      int r = lch * 8 + k2;
      int idx = r * 128 + (((d >> 3) ^ (lch & 7)) << 3) + (d & 7);
      vals[k2] = sT[idx];
    }
    bf16x8 o;
#pragma unroll
    for (int k2 = 0; k2 < 8; k2++) o[k2] = (short)vals[k2];
    *(bf16x8*)(outp + (u64)d * 512 + l0 + lch * 8) = o;
  }
}

// ---- flash attention, fixed-max softmax. Block = 128 q rows, 4 waves x 32 q.
// Q cols [0,768), K cols [768,1536) of QKV[m][2304]; VT: [b,h,96,512].
#define PST 36
__global__ __launch_bounds__(256) void attn_kernel(
    const u16* __restrict__ QKV, const u16* __restrict__ VT, u16* __restrict__ ctxb)
{
  __shared__ __align__(16) u16 sK[32 * 96];
  __shared__ __align__(16) u16 sV[32 * 96];
  __shared__ __align__(16) u16 sP[4][16 * PST];
  const int tid = threadIdx.x, lane = tid & 63, wid = tid >> 6;
  int fid = blockIdx.x;
  int xcd = fid & 7, slot = (fid >> 3) & 3, grp = fid >> 5;
  int bh = grp * 8 + xcd;
  int b = bh >> 3, h = bh & 7;
  int q0 = slot * 128;
  const int fr = lane & 15, fq = lane >> 4;
  const u64 mb = (u64)(b * 511);
  const u64 hbV = (u64)bh * 96 * 512;

  bf16x8 qf[2][3];
#pragma unroll
  for (int sub = 0; sub < 2; sub++) {
    int qr = q0 + wid * 32 + sub * 16 + fr; if (qr > 510) qr = 510;
#pragma unroll
    for (int ks = 0; ks < 3; ks++)
      qf[sub][ks] = *(const bf16x8*)(QKV + (mb + qr) * 2304 + h * 96 + ks * 32 + fq * 8);
  }

  f32x4 ctx[2][6] = {};
  f32x4 sumP[2] = {};

  int cK1 = wid * 64 + lane;
  int kr1 = cK1 / 12, kc1 = cK1 - kr1 * 12;
  const u16* gK1 = QKV + (mb + kr1) * 2304 + 768 + h * 96 + kc1 * 8;
  int cK2 = 256 + cK1;
  int kr2 = cK2 / 12, kc2 = cK2 - kr2 * 12;
  const u16* gK2 = QKV + (mb + kr2) * 2304 + 768 + h * 96 + kc2 * 8;
  int cV1 = wid * 64 + lane;
  int dV1 = cV1 >> 2, jV1 = (cV1 & 3) ^ ((dV1 >> 1) & 3);
  const u16* gV1 = VT + hbV + (u64)dV1 * 512 + jV1 * 8;
  int cV2 = 256 + (wid - 2) * 64 + lane;
  int dV2 = cV2 >> 2, jV2 = (cV2 & 3) ^ ((dV2 >> 1) & 3);
  const u16* gV2 = VT + hbV + (u64)dV2 * 512 + jV2 * 8;

  u16* lK1 = sK + (u32)(wid * 64) * 8;
  u16* lK2 = sK + (u32)(256 + wid * 64) * 8;
  u16* lV1 = sV + (u32)(wid * 64) * 8;
  u16* lV2 = sV + (u32)(256 + (wid - 2) * 64) * 8;
  u16* pw = &sP[wid][0];

  const float cs = 0.10206207261596575f; // 1/sqrt(96)
  const int cpx = fq ^ ((fr >> 1) & 3);

  for (int kv0 = 0; kv0 < 511; kv0 += 32) {
    __syncthreads();
    gld_lds16(gK1, lK1); gK1 += (u64)32 * 2304;
    if (wid < 2) { gld_lds16(gK2, lK2); gK2 += (u64)32 * 2304; }
    gld_lds16(gV1, lV1); gV1 += 32;
    if (wid >= 2) { gld_lds16(gV2, lV2); gV2 += 32; }
    __syncthreads();

    bf16x8 kf0[3], kf1[3];
#pragma unroll
    for (int ks = 0; ks < 3; ks++) {
      kf0[ks] = *(const bf16x8*)(sK + fr * 96 + ks * 32 + fq * 8);
      kf1[ks] = *(const bf16x8*)(sK + (16 + fr) * 96 + ks * 32 + fq * 8);
    }
    const bool ok1 = (kv0 + 16 + fr) < Ll;

#pragma unroll
    for (int sub = 0; sub < 2; sub++) {
      f32x4 s0 = {}, s1 = {};
#pragma unroll
      for (int ks = 0; ks < 3; ks++) {
        s0 = MFMA16(qf[sub][ks], kf0[ks], s0);
        s1 = MFMA16(qf[sub][ks], kf1[ks], s1);
      }
      float p0[4], p1[4];
#pragma unroll
      for (int r = 0; r < 4; r++) {
        p0[r] = __expf(s0[r] * cs);
        float e1 = __expf(s1[r] * cs);
        p1[r] = ok1 ? e1 : 0.f;
        sumP[sub][r] += p0[r] + p1[r];
      }
#pragma unroll
      for (int r = 0; r < 4; r++) {
        int row = fq * 4 + r;
        pw[row * PST + fr] = f2b(p0[r]);
        pw[row * PST + 16 + fr] = f2b(p1[r]);
      }
      bf16x8 pf = *(const bf16x8*)(pw + fr * PST + fq * 8);
#pragma unroll
      for (int df = 0; df < 6; df++) {
        bf16x8 vf = *(const bf16x8*)(sV + (df * 16 + fr) * 32 + cpx * 8);
        ctx[sub][df] = MFMA16(pf, vf, ctx[sub][df]);
      }
    }
  }

#pragma unroll
  for (int sub = 0; sub < 2; sub++) {
    float inv[4];
#pragma unroll
    for (int r = 0; r < 4; r++) {
      float s = sumP[sub][r];
      s += __shfl_xor(s, 1, 64);
      s += __shfl_xor(s, 2, 64);
      s += __shfl_xor(s, 4, 64);
      s += __shfl_xor(s, 8, 64);
      inv[r] = 1.f / s;
    }
#pragma unroll
    for (int df = 0; df < 6; df++) {
#pragma unroll
      for (int r = 0; r < 4; r++) {
        int q = q0 + wid * 32 + sub * 16 + fq * 4 + r;
        if (q < Ll)
          ctxb[(u64)(b * Ll + q) * 768 + h * 96 + df * 16 + fr] = f2b(ctx[sub][df][r] * inv[r]);
      }
    }
  }
}

// ---- per-channel sums over rows (bf16 input)
__global__ __launch_bounds__(256) void stats_kernel(const u16* __restrict__ ao,
                                                    float* __restrict__ ssum, float* __restrict__ ssq)
{
  int t = threadIdx.x;
  int row0 = blockIdx.x * 128;
  int rowEnd = row0 + 128; if (rowEnd > Mrows) rowEnd = Mrows;
  float s[3] = {0.f, 0.f, 0.f}, q[3] = {0.f, 0.f, 0.f};
  for (int m = row0; m < rowEnd; m++) {
    const u16* rp = ao + (u64)m * 768;
#pragma unroll
    for (int i = 0; i < 3; i++) {
      float v = b2f(rp[t + i * 256]);
      s[i] += v; q[i] += v * v;
    }
  }
#pragma unroll
  for (int i = 0; i < 3; i++) {
    atomicAdd(&ssum[t + i * 256], s[i]);
    atomicAdd(&ssq[t + i * 256], q[i]);
  }
}

__global__ __launch_bounds__(256) void derived_kernel(
    const float* __restrict__ ssum, const float* __restrict__ ssq,
    const float* __restrict__ w_out, const float* __restrict__ b_out,
    const float* __restrict__ gamma, const float* __restrict__ beta,
    float* __restrict__ weff, float* __restrict__ consts)
{
  __shared__ float red[256];
  int t = threadIdx.x;
  float acc = 0.f;
  const float invN = 1.f / 32704.f;
#pragma unroll
  for (int i = 0; i < 3; i++) {
    int hh = t + i * 256;
    float mu = ssum[hh] * invN;
    float var = ssq[hh] * invN - mu * mu;
    float rstd = 1.f / sqrtf(var + 1e-5f);
    float we = w_out[hh] * gamma[hh] * rstd;
    weff[hh] = we;
    acc += w_out[hh] * beta[hh] - we * mu;
  }
  red[t] = acc; __syncthreads();
  for (int s = 128; s > 0; s >>= 1) { if (t < s) red[t] += red[t + s]; __syncthreads(); }
  if (t == 0) consts[0] = b_out[0] + red[0];
}

// ---- fv[m] = dot(c_row, w_out) + dot(a_row, weff) + const   (one wave per row)
__global__ __launch_bounds__(256) void fv_kernel(
    const u16* __restrict__ ao, const u16* __restrict__ cb,
    const float* __restrict__ w_out, const float* __restrict__ weff,
    const float* __restrict__ consts, float* __restrict__ fv)
{
  int lane = threadIdx.x & 63, wid = threadIdx.x >> 6;
  int m = blockIdx.x * 4 + wid;
  if (m >= Mrows) return;
  const u16* ap = ao + (u64)m * 768;
  const u16* cp = cb + (u64)m * 768;
  float acc = 0.f;
#pragma unroll
  for (int i = 0; i < 12; i++) {
    int hh = lane + i * 64;
    acc += b2f(ap[hh]) * weff[hh] + b2f(cp[hh]) * w_out[hh];
  }
#pragma unroll
  for (int off = 1; off < 64; off <<= 1) acc += __shfl_xor(acc, off, 64);
  if (lane == 0) fv[m] = acc + consts[0];
}

// ---- comma-delimited segment means, one wave per batch row
__global__ __launch_bounds__(64) void seg_kernel(
    const float* __restrict__ fv, const int* __restrict__ ids, float* __restrict__ out)
{
  __shared__ float ssum[NSEG];
  __shared__ int scnt[NSEG];
  int lane = threadIdx.x;
  int b = blockIdx.x;
  if (lane < NSEG) { ssum[lane] = 0.f; scnt[lane] = 0; }
  __syncthreads();
  int carry = 0;
  for (int it = 0; it < 8; it++) {
    int l = it * 64 + lane;
    bool active = l < Ll;
    int id = active ? ids[b * 512 + l] : 0;
    bool comma = active && (id == COMMA_IDC);
    u64 cmask = __ballot(comma);
    int seg = carry + __popcll(cmask & ((1ull << lane) - 1ull));
    bool valid = active && (l >= 1) && !comma;
    if (valid && seg < NSEG) {
      atomicAdd(&ssum[seg], fv[b * Ll + l]);
      atomicAdd(&scnt[seg], 1);
    }
    carry += __popcll(cmask);
  }
  __syncthreads();
  if (lane < NSEG) {
    float c = (float)scnt[lane];
    out[b * NSEG + lane] = ssum[lane] / fmaxf(c, 1.f);
  }
}

extern "C" void kernel_launch(void* const* d_in, const int* in_sizes, int n_in,
                              void* d_out, int out_size, void* d_ws, size_t ws_size,
                              hipStream_t stream)
{
  const float* text  = (const float*)d_in[0];
  const float* cols  = (const float*)d_in[1];
  const float* wq    = (const float*)d_in[2];
  const float* wk    = (const float*)d_in[3];
  const float* wvp   = (const float*)d_in[4];
  const float* bq    = (const float*)d_in[5];
  const float* bk    = (const float*)d_in[6];
  const float* bv    = (const float*)d_in[7];
  const float* wo    = (const float*)d_in[8];
  const float* bo    = (const float*)d_in[9];
  const float* gamma = (const float*)d_in[10];
  const float* beta  = (const float*)d_in[11];
  const float* w_out = (const float*)d_in[12];
  const float* b_out = (const float*)d_in[13];
  const int*   ids   = (const int*)d_in[14];
  float* out = (float*)d_out;

  char* ws = (char*)d_ws;
  u16* cb    = (u16*)(ws + 0ull);             // [32768][768] bf16 (sliced cols), live till fv
  u16* tb    = (u16*)(ws + 50331648ull);      // [32768][768] bf16; VTb reuses after QKV gemm
  u16* wqkvb = (u16*)(ws + 100663296ull);     // [2304][768] bf16 (wq|wk|wv rows)
  u16* wob   = (u16*)(ws + 104202240ull);     // [768][768] bf16
  u16* QKVb  = (u16*)(ws + 105381888ull);     // [32768][2304] bf16; aob + stats reuse after attn
  u16* ctxb  = (u16*)(ws + 256376832ull);     // [32768][768] bf16 (attn out)
  u16* VTb   = tb;                             // [64][8][96][512] bf16
  u16* aob   = QKVb;                           // [32768][768] bf16 (gemm2 out)
  float* ssum   = (float*)(ws + 105381888ull + 50331648ull); // QKV K-region, dead after attn
  float* ssq    = ssum + 768;
  float* weff   = ssum + 1536;
  float* consts = ssum + 2304;
  float* fv     = (float*)((char*)ssum + 16384ull);

  conv_sliced<<<dim3(384, 64), 256, 0, stream>>>((const float4*)cols, (ushort4*)cb);
  conv_sliced<<<dim3(384, 64), 256, 0, stream>>>((const float4*)text, (ushort4*)tb);
  conv_flat<<<576, 256, 0, stream>>>((const float4*)wq, (ushort4*)wqkvb, 147456);
  conv_flat<<<576, 256, 0, stream>>>((const float4*)wk, (ushort4*)(wqkvb + 589824), 147456);
  conv_flat<<<576, 256, 0, stream>>>((const float4*)wvp, (ushort4*)(wqkvb + 1179648), 147456);
  conv_flat<<<576, 256, 0, stream>>>((const float4*)wo, (ushort4*)wob, 147456);

  // QKV: out [m][2304]; n-tiles 0-5 use cb (Q), 6-17 use tb (K,V)
  gemmk<18, 2304, 6><<<4608, 256, 0, stream>>>(cb, tb, wqkvb, bq, bk, bv, QKVb);
  vtrans<<<dim3(4, 512), 256, 0, stream>>>(QKVb, VTb);
  attn_kernel<<<2048, 256, 0, stream>>>(QKVb, VTb, ctxb);

  zero_kernel<<<6, 256, 0, stream>>>(ssum, 1536);
  gemmk<6, 768, 99><<<1536, 256, 0, stream>>>(ctxb, ctxb, wob, bo, bo, bo, aob);
  stats_kernel<<<256, 256, 0, stream>>>(aob, ssum, ssq);
  derived_kernel<<<1, 256, 0, stream>>>(ssum, ssq, w_out, b_out, gamma, beta, weff, consts);
  fv_kernel<<<8176, 256, 0, stream>>>(aob, cb, w_out, weff, consts, fv);
  seg_kernel<<<64, 64, 0, stream>>>(fv, ids, out);
}

// Round 4
// 460.189 us; speedup vs baseline: 1.3525x; 1.0047x over previous
//
#include <hip/hip_runtime.h>
#include <hip/hip_bf16.h>

#define COMMA_IDC 1010
#define NHEAD 8
#define Ll 511
#define Mrows 32704
#define NSEG 17

typedef __attribute__((ext_vector_type(8))) short bf16x8;
typedef __attribute__((ext_vector_type(4))) float f32x4;
typedef unsigned short u16;
typedef unsigned int u32;
typedef unsigned long long u64;

__device__ __forceinline__ u16 f2b(float f) {
  __hip_bfloat16 h = __float2bfloat16(f);
  return *reinterpret_cast<u16*>(&h);
}
__device__ __forceinline__ float b2f(u16 u) {
  u32 x = ((u32)u) << 16;
  return __builtin_bit_cast(float, x);
}

__device__ __forceinline__ void gld_lds16(const void* g, void* l) {
  __builtin_amdgcn_global_load_lds(
      (const __attribute__((address_space(1))) void*)(u64)g,
      (__attribute__((address_space(3))) void*)(u32)(u64)l,
      16, 0, 0);
}

#define MFMA16(a, b, c) __builtin_amdgcn_mfma_f32_16x16x32_bf16(a, b, c, 0, 0, 0)

// ---- convert f32 -> bf16, slicing off token 0; z=0: cols->cb, z=1: text->tb
__global__ void conv_sliced2(const float4* __restrict__ s0, const float4* __restrict__ s1,
                             ushort4* __restrict__ d0, ushort4* __restrict__ d1) {
  const float4* src = blockIdx.z ? s1 : s0;
  ushort4* dst = blockIdx.z ? d1 : d0;
  int b = blockIdx.y;
  int idx = blockIdx.x * 256 + threadIdx.x;
  if (idx >= Ll * 192) return;
  int l = idx / 192, c = idx - l * 192;
  float4 v = src[(b * 512 + l + 1) * 192 + c];
  ushort4 o; o.x = f2b(v.x); o.y = f2b(v.y); o.z = f2b(v.z); o.w = f2b(v.w);
  dst[(b * Ll + l) * 192 + c] = o;
}

// ---- all 4 weight matrices in one launch: wq|wk|wv -> wqkvb, wo -> wob
__global__ void conv_w(const float4* __restrict__ wq, const float4* __restrict__ wk,
                       const float4* __restrict__ wv, const float4* __restrict__ wo,
                       ushort4* __restrict__ wqkvb, ushort4* __restrict__ wob) {
  int i = blockIdx.x * 256 + threadIdx.x;   // 0 .. 4*147456
  int seg = i / 147456, off = i - seg * 147456;
  const float4* s = (seg == 0) ? wq : ((seg == 1) ? wk : ((seg == 2) ? wv : wo));
  ushort4* d = (seg == 3) ? wob : (wqkvb + seg * 147456);
  float4 v = s[off];
  ushort4 o; o.x = f2b(v.x); o.y = f2b(v.y); o.z = f2b(v.z); o.w = f2b(v.w);
  d[off] = o;
}

__global__ void zero_kernel(float* p, int n) {
  int i = blockIdx.x * 256 + threadIdx.x;
  if (i < n) p[i] = 0.f;
}

// ============ 256x256x(K=768) bf16 MFMA GEMM, 8-phase schedule ============
// C = A @ W^T + bias, out [m][NOUT] bf16. W [N][768] row-major.
// 512 thr / 8 waves (2M x 4N), BK=64, 128KB LDS dbuf, chunk-XOR swizzle,
// counted in-flight loads (issue all 4 half-tiles at phase 0, drain at phase 3).
// A = (ncol < QNT) ? A0 : A1; bias by 768-col segment.
#define LDA_(i, kk) (*(const bf16x8*)(sMem + bA + ((i) * 16 + fr) * 64 + ((((kk) * 4 + fq) ^ xm) << 3)))
#define LDW_(j, kk) (*(const bf16x8*)(sMem + bW + (((wc * 64 + (j) * 16) >> 7) * 8192) + \
                     (((wc * 64 + (j) * 16) & 127) + fr) * 64 + ((((kk) * 4 + fq) ^ xm) << 3)))
#define LGKM0 do { asm volatile("s_waitcnt lgkmcnt(0)" ::: "memory"); __builtin_amdgcn_sched_barrier(0); } while (0)

template<int NTILES, int NOUT, int QNT>
__global__ __launch_bounds__(512, 2) void gemm256(
    const u16* __restrict__ A0, const u16* __restrict__ A1, const u16* __restrict__ W,
    const float* __restrict__ b0, const float* __restrict__ b1, const float* __restrict__ b2,
    u16* __restrict__ outp)
{
  __shared__ __align__(16) u16 sMem[65536];  // 128 KB: [buf][A/W][half][128 rows][64 k]
  const int tid = threadIdx.x;
  const int lane = tid & 63, wid = tid >> 6;
  const int fr = lane & 15, fq = lane >> 4;
  const int wr = wid >> 2, wc = wid & 3;
  const int xm = fr & 7;

  int fid = blockIdx.x;
  int xcd = fid & 7, w = fid >> 3;
  int mrow = xcd * 16 + w / NTILES;
  int ncol = w - (w / NTILES) * NTILES;
  const int m0 = mrow * 256, n0 = ncol * 256;
  const u16* __restrict__ A = (ncol < QNT) ? A0 : A1;

  // staging geometry: thread t covers 16B-chunks t and t+512 of each half-tile.
  // LDS pos (r,p) holds global chunk p^(r&7)  (both chunks share r&7).
  const int rS = tid >> 3;
  const int cS = (tid & 7) ^ (rS & 7);
  const u16* gA0 = A + (u64)(m0 + rS) * 768 + cS * 8;
  const u16* gA1 = A + (u64)(m0 + 128 + rS) * 768 + cS * 8;
  const u16* gW0 = W + (u64)(n0 + rS) * 768 + cS * 8;
  const u16* gW1 = W + (u64)(n0 + 128 + rS) * 768 + cS * 8;
  const u32 st0 = tid * 8;

  f32x4 acc[8][4] = {};

  auto stage_all = [&](int buf, int kt) {
    const int kb = kt * 64;
    const u32 db = (u32)buf * 32768;
    gld_lds16(gA0 + kb, sMem + db + st0);
    gld_lds16(gA0 + kb + 49152, sMem + db + st0 + 4096);
    gld_lds16(gA1 + kb, sMem + db + 8192 + st0);
    gld_lds16(gA1 + kb + 49152, sMem + db + 8192 + st0 + 4096);
    gld_lds16(gW0 + kb, sMem + db + 16384 + st0);
    gld_lds16(gW0 + kb + 49152, sMem + db + 16384 + st0 + 4096);
    gld_lds16(gW1 + kb, sMem + db + 24576 + st0);
    gld_lds16(gW1 + kb + 49152, sMem + db + 24576 + st0 + 4096);
  };

  stage_all(0, 0);
  asm volatile("s_waitcnt vmcnt(0)" ::: "memory");
  __builtin_amdgcn_s_barrier();

  for (int kt = 0; kt < 12; ++kt) {
    const u32 db = (u32)(kt & 1) * 32768;
    const u32 bA = db + wr * 8192;
    const u32 bW = db + 16384;
    bf16x8 af[4][2], wf[2][2];

    // ---- phase 0: quadrant (0,0); issue next K-tile's 8 loads
#pragma unroll
    for (int i = 0; i < 4; i++) { af[i][0] = LDA_(i, 0); af[i][1] = LDA_(i, 1); }
#pragma unroll
    for (int j = 0; j < 2; j++) { wf[j][0] = LDW_(j, 0); wf[j][1] = LDW_(j, 1); }
    __builtin_amdgcn_s_barrier();
    if (kt + 1 < 12) stage_all((kt + 1) & 1, kt + 1);
    LGKM0;
    __builtin_amdgcn_s_setprio(1);
#pragma unroll
    for (int i = 0; i < 4; i++)
#pragma unroll
      for (int j = 0; j < 2; j++) {
        acc[i][j] = MFMA16(af[i][0], wf[j][0], acc[i][j]);
        acc[i][j] = MFMA16(af[i][1], wf[j][1], acc[i][j]);
      }
    __builtin_amdgcn_s_setprio(0);
    __builtin_amdgcn_s_barrier();

    // ---- phase 1: quadrant (0,1)
#pragma unroll
    for (int j = 0; j < 2; j++) { wf[j][0] = LDW_(j + 2, 0); wf[j][1] = LDW_(j + 2, 1); }
    __builtin_amdgcn_s_barrier();
    LGKM0;
    __builtin_amdgcn_s_setprio(1);
#pragma unroll
    for (int i = 0; i < 4; i++)
#pragma unroll
      for (int j = 0; j < 2; j++) {
        acc[i][j + 2] = MFMA16(af[i][0], wf[j][0], acc[i][j + 2]);
        acc[i][j + 2] = MFMA16(af[i][1], wf[j][1], acc[i][j + 2]);
      }
    __builtin_amdgcn_s_setprio(0);
    __builtin_amdgcn_s_barrier();

    // ---- phase 2: quadrant (1,0)
#pragma unroll
    for (int i = 0; i < 4; i++) { af[i][0] = LDA_(i + 4, 0); af[i][1] = LDA_(i + 4, 1); }
#pragma unroll
    for (int j = 0; j < 2; j++) { wf[j][0] = LDW_(j, 0); wf[j][1] = LDW_(j, 1); }
    __builtin_amdgcn_s_barrier();
    LGKM0;
    __builtin_amdgcn_s_setprio(1);
#pragma unroll
    for (int i = 0; i < 4; i++)
#pragma unroll
      for (int j = 0; j < 2; j++) {
        acc[i + 4][j] = MFMA16(af[i][0], wf[j][0], acc[i + 4][j]);
        acc[i + 4][j] = MFMA16(af[i][1], wf[j][1], acc[i + 4][j]);
      }
    __builtin_amdgcn_s_setprio(0);
    __builtin_amdgcn_s_barrier();

    // ---- phase 3: quadrant (1,1); drain this-tile's prefetch before buffer swap
#pragma unroll
    for (int j = 0; j < 2; j++) { wf[j][0] = LDW_(j + 2, 0); wf[j][1] = LDW_(j + 2, 1); }
    __builtin_amdgcn_s_barrier();
    LGKM0;
    __builtin_amdgcn_s_setprio(1);
#pragma unroll
    for (int i = 0; i < 4; i++)
#pragma unroll
      for (int j = 0; j < 2; j++) {
        acc[i + 4][j + 2] = MFMA16(af[i][0], wf[j][0], acc[i + 4][j + 2]);
        acc[i + 4][j + 2] = MFMA16(af[i][1], wf[j][1], acc[i + 4][j + 2]);
      }
    __builtin_amdgcn_s_setprio(0);
    asm volatile("s_waitcnt vmcnt(0)" ::: "memory");
    __builtin_amdgcn_s_barrier();
  }

  // ---- epilogue: bias + LDS restage (stride 264) -> coalesced bf16x8 stores
  const float* bp = (n0 < 768) ? b0 : ((n0 < 1536) ? b1 : b2);
  const int bcol = n0 & 767;
  float bj[4];
#pragma unroll
  for (int j = 0; j < 4; j++) bj[j] = bp[bcol + wc * 64 + j * 16 + fr];

#pragma unroll
  for (int h = 0; h < 2; h++) {
    __syncthreads();
    if (wr == h) {
#pragma unroll
      for (int i = 0; i < 8; i++)
#pragma unroll
        for (int j = 0; j < 4; j++)
#pragma unroll
          for (int r = 0; r < 4; r++)
            sMem[(i * 16 + fq * 4 + r) * 264 + wc * 64 + j * 16 + fr] = f2b(acc[i][j][r] + bj[j]);
    }
    __syncthreads();
#pragma unroll
    for (int it = 0; it < 8; it++) {
      int chunk = tid + it * 512;
      int lr = chunk >> 5, ch = chunk & 31;
      *(bf16x8*)(outp + (u64)(m0 + h * 128 + lr) * NOUT + n0 + ch * 8) =
          *(const bf16x8*)(sMem + lr * 264 + ch * 8);
    }
  }
}

// ---- V transpose: QKV[m][2304] V-cols -> VT [b,h,96,512], XOR-swizzled LDS tile
__global__ __launch_bounds__(256) void vtrans(const u16* __restrict__ QKV, u16* __restrict__ VT) {
  __shared__ __align__(16) u16 sT[128 * 128];
  int bh = blockIdx.y;
  int b = bh >> 3, h = bh & 7;
  int l0 = blockIdx.x * 128;
  u16* outp = VT + (u64)bh * 96 * 512;
  int t = threadIdx.x;
#pragma unroll
  for (int k = 0; k < 6; k++) {
    int c = t + k * 256;
    int l = c / 12, ch = c - l * 12;
    int lc = l0 + l; if (lc > 510) lc = 510;
    bf16x8 v = *(const bf16x8*)(QKV + (u64)(b * 511 + lc) * 2304 + 1536 + h * 96 + ch * 8);
    int chunk = l * 16 + (ch ^ ((l >> 3) & 7));
    *(bf16x8*)(sT + chunk * 8) = v;
  }
  __syncthreads();
#pragma unroll
  for (int k = 0; k < 6; k++) {
    int c = t + k * 256;
    int d = c >> 4, lch = c & 15;
    u16 vals[8];
#pragma unroll
    for (int k2 = 0; k2 < 8; k2++) {
      int r = lch * 8 + k2;
      int idx = r * 128 + (((d >> 3) ^ (lch & 7)) << 3) + (d & 7);
      vals[k2] = sT[idx];
    }
    bf16x8 o;
#pragma unroll
    for (int k2 = 0; k2 < 8; k2++) o[k2] = (short)vals[k2];
    *(bf16x8*)(outp + (u64)d * 512 + l0 + lch * 8) = o;
  }
}

// ---- flash attention, fixed-max softmax. Block = 128 q rows, 4 waves x 32 q.
#define PST 36
__global__ __launch_bounds__(256) void attn_kernel(
    const u16* __restrict__ QKV, const u16* __restrict__ VT, u16* __restrict__ ctxb)
{
  __shared__ __align__(16) u16 sK[32 * 96];
  __shared__ __align__(16) u16 sV[32 * 96];
  __shared__ __align__(16) u16 sP[4][16 * PST];
  const int tid = threadIdx.x, lane = tid & 63, wid = tid >> 6;
  int fid = blockIdx.x;
  int xcd = fid & 7, slot = (fid >> 3) & 3, grp = fid >> 5;
  int bh = grp * 8 + xcd;
  int b = bh >> 3, h = bh & 7;
  int q0 = slot * 128;
  const int fr = lane & 15, fq = lane >> 4;
  const u64 mb = (u64)(b * 511);
  const u64 hbV = (u64)bh * 96 * 512;

  bf16x8 qf[2][3];
#pragma unroll
  for (int sub = 0; sub < 2; sub++) {
    int qr = q0 + wid * 32 + sub * 16 + fr; if (qr > 510) qr = 510;
#pragma unroll
    for (int ks = 0; ks < 3; ks++)
      qf[sub][ks] = *(const bf16x8*)(QKV + (mb + qr) * 2304 + h * 96 + ks * 32 + fq * 8);
  }

  f32x4 ctx[2][6] = {};
  f32x4 sumP[2] = {};

  int cK1 = wid * 64 + lane;
  int kr1 = cK1 / 12, kc1 = cK1 - kr1 * 12;
  const u16* gK1 = QKV + (mb + kr1) * 2304 + 768 + h * 96 + kc1 * 8;
  int cK2 = 256 + cK1;
  int kr2 = cK2 / 12, kc2 = cK2 - kr2 * 12;
  const u16* gK2 = QKV + (mb + kr2) * 2304 + 768 + h * 96 + kc2 * 8;
  int cV1 = wid * 64 + lane;
  int dV1 = cV1 >> 2, jV1 = (cV1 & 3) ^ ((dV1 >> 1) & 3);
  const u16* gV1 = VT + hbV + (u64)dV1 * 512 + jV1 * 8;
  int cV2 = 256 + (wid - 2) * 64 + lane;
  int dV2 = cV2 >> 2, jV2 = (cV2 & 3) ^ ((dV2 >> 1) & 3);
  const u16* gV2 = VT + hbV + (u64)dV2 * 512 + jV2 * 8;

  u16* lK1 = sK + (u32)(wid * 64) * 8;
  u16* lK2 = sK + (u32)(256 + wid * 64) * 8;
  u16* lV1 = sV + (u32)(wid * 64) * 8;
  u16* lV2 = sV + (u32)(256 + (wid - 2) * 64) * 8;
  u16* pw = &sP[wid][0];

  const float cs = 0.10206207261596575f; // 1/sqrt(96)
  const int cpx = fq ^ ((fr >> 1) & 3);

  for (int kv0 = 0; kv0 < 511; kv0 += 32) {
    __syncthreads();
    gld_lds16(gK1, lK1); gK1 += (u64)32 * 2304;
    if (wid < 2) { gld_lds16(gK2, lK2); gK2 += (u64)32 * 2304; }
    gld_lds16(gV1, lV1); gV1 += 32;
    if (wid >= 2) { gld_lds16(gV2, lV2); gV2 += 32; }
    __syncthreads();

    bf16x8 kf0[3], kf1[3];
#pragma unroll
    for (int ks = 0; ks < 3; ks++) {
      kf0[ks] = *(const bf16x8*)(sK + fr * 96 + ks * 32 + fq * 8);
      kf1[ks] = *(const bf16x8*)(sK + (16 + fr) * 96 + ks * 32 + fq * 8);
    }
    const bool ok1 = (kv0 + 16 + fr) < Ll;

#pragma unroll
    for (int sub = 0; sub < 2; sub++) {
      f32x4 s0 = {}, s1 = {};
#pragma unroll
      for (int ks = 0; ks < 3; ks++) {
        s0 = MFMA16(qf[sub][ks], kf0[ks], s0);
        s1 = MFMA16(qf[sub][ks], kf1[ks], s1);
      }
      float p0[4], p1[4];
#pragma unroll
      for (int r = 0; r < 4; r++) {
        p0[r] = __expf(s0[r] * cs);
        float e1 = __expf(s1[r] * cs);
        p1[r] = ok1 ? e1 : 0.f;
        sumP[sub][r] += p0[r] + p1[r];
      }
#pragma unroll
      for (int r = 0; r < 4; r++) {
        int row = fq * 4 + r;
        pw[row * PST + fr] = f2b(p0[r]);
        pw[row * PST + 16 + fr] = f2b(p1[r]);
      }
      bf16x8 pf = *(const bf16x8*)(pw + fr * PST + fq * 8);
#pragma unroll
      for (int df = 0; df < 6; df++) {
        bf16x8 vf = *(const bf16x8*)(sV + (df * 16 + fr) * 32 + cpx * 8);
        ctx[sub][df] = MFMA16(pf, vf, ctx[sub][df]);
      }
    }
  }

#pragma unroll
  for (int sub = 0; sub < 2; sub++) {
    float inv[4];
#pragma unroll
    for (int r = 0; r < 4; r++) {
      float s = sumP[sub][r];
      s += __shfl_xor(s, 1, 64);
      s += __shfl_xor(s, 2, 64);
      s += __shfl_xor(s, 4, 64);
      s += __shfl_xor(s, 8, 64);
      inv[r] = 1.f / s;
    }
#pragma unroll
    for (int df = 0; df < 6; df++) {
#pragma unroll
      for (int r = 0; r < 4; r++) {
        int q = q0 + wid * 32 + sub * 16 + fq * 4 + r;
        if (q < Ll)
          ctxb[(u64)(b * Ll + q) * 768 + h * 96 + df * 16 + fr] = f2b(ctx[sub][df][r] * inv[r]);
      }
    }
  }
}

// ---- per-channel sums over rows (bf16 input)
__global__ __launch_bounds__(256) void stats_kernel(const u16* __restrict__ ao,
                                                    float* __restrict__ ssum, float* __restrict__ ssq)
{
  int t = threadIdx.x;
  int row0 = blockIdx.x * 128;
  int rowEnd = row0 + 128; if (rowEnd > Mrows) rowEnd = Mrows;
  float s[3] = {0.f, 0.f, 0.f}, q[3] = {0.f, 0.f, 0.f};
  for (int m = row0; m < rowEnd; m++) {
    const u16* rp = ao + (u64)m * 768;
#pragma unroll
    for (int i = 0; i < 3; i++) {
      float v = b2f(rp[t + i * 256]);
      s[i] += v; q[i] += v * v;
    }
  }
#pragma unroll
  for (int i = 0; i < 3; i++) {
    atomicAdd(&ssum[t + i * 256], s[i]);
    atomicAdd(&ssq[t + i * 256], q[i]);
  }
}

__global__ __launch_bounds__(256) void derived_kernel(
    const float* __restrict__ ssum, const float* __restrict__ ssq,
    const float* __restrict__ w_out, const float* __restrict__ b_out,
    const float* __restrict__ gamma, const float* __restrict__ beta,
    float* __restrict__ weff, float* __restrict__ consts)
{
  __shared__ float red[256];
  int t = threadIdx.x;
  float acc = 0.f;
  const float invN = 1.f / 32704.f;
#pragma unroll
  for (int i = 0; i < 3; i++) {
    int hh = t + i * 256;
    float mu = ssum[hh] * invN;
    float var = ssq[hh] * invN - mu * mu;
    float rstd = 1.f / sqrtf(var + 1e-5f);
    float we = w_out[hh] * gamma[hh] * rstd;
    weff[hh] = we;
    acc += w_out[hh] * beta[hh] - we * mu;
  }
  red[t] = acc; __syncthreads();
  for (int s = 128; s > 0; s >>= 1) { if (t < s) red[t] += red[t + s]; __syncthreads(); }
  if (t == 0) consts[0] = b_out[0] + red[0];
}

// ---- fv[m] = dot(c_row, w_out) + dot(a_row, weff) + const   (one wave per row)
__global__ __launch_bounds__(256) void fv_kernel(
    const u16* __restrict__ ao, const u16* __restrict__ cb,
    const float* __restrict__ w_out, const float* __restrict__ weff,
    const float* __restrict__ consts, float* __restrict__ fv)
{
  int lane = threadIdx.x & 63, wid = threadIdx.x >> 6;
  int m = blockIdx.x * 4 + wid;
  if (m >= Mrows) return;
  const u16* ap = ao + (u64)m * 768;
  const u16* cp = cb + (u64)m * 768;
  float acc = 0.f;
#pragma unroll
  for (int i = 0; i < 12; i++) {
    int hh = lane + i * 64;
    acc += b2f(ap[hh]) * weff[hh] + b2f(cp[hh]) * w_out[hh];
  }
#pragma unroll
  for (int off = 1; off < 64; off <<= 1) acc += __shfl_xor(acc, off, 64);
  if (lane == 0) fv[m] = acc + consts[0];
}

// ---- comma-delimited segment means, one wave per batch row
__global__ __launch_bounds__(64) void seg_kernel(
    const float* __restrict__ fv, const int* __restrict__ ids, float* __restrict__ out)
{
  __shared__ float ssum[NSEG];
  __shared__ int scnt[NSEG];
  int lane = threadIdx.x;
  int b = blockIdx.x;
  if (lane < NSEG) { ssum[lane] = 0.f; scnt[lane] = 0; }
  __syncthreads();
  int carry = 0;
  for (int it = 0; it < 8; it++) {
    int l = it * 64 + lane;
    bool active = l < Ll;
    int id = active ? ids[b * 512 + l] : 0;
    bool comma = active && (id == COMMA_IDC);
    u64 cmask = __ballot(comma);
    int seg = carry + __popcll(cmask & ((1ull << lane) - 1ull));
    bool valid = active && (l >= 1) && !comma;
    if (valid && seg < NSEG) {
      atomicAdd(&ssum[seg], fv[b * Ll + l]);
      atomicAdd(&scnt[seg], 1);
    }
    carry += __popcll(cmask);
  }
  __syncthreads();
  if (lane < NSEG) {
    float c = (float)scnt[lane];
    out[b * NSEG + lane] = ssum[lane] / fmaxf(c, 1.f);
  }
}

extern "C" void kernel_launch(void* const* d_in, const int* in_sizes, int n_in,
                              void* d_out, int out_size, void* d_ws, size_t ws_size,
                              hipStream_t stream)
{
  const float* text  = (const float*)d_in[0];
  const float* cols  = (const float*)d_in[1];
  const float* wq    = (const float*)d_in[2];
  const float* wk    = (const float*)d_in[3];
  const float* wvp   = (const float*)d_in[4];
  const float* bq    = (const float*)d_in[5];
  const float* bk    = (const float*)d_in[6];
  const float* bv    = (const float*)d_in[7];
  const float* wo    = (const float*)d_in[8];
  const float* bo    = (const float*)d_in[9];
  const float* gamma = (const float*)d_in[10];
  const float* beta  = (const float*)d_in[11];
  const float* w_out = (const float*)d_in[12];
  const float* b_out = (const float*)d_in[13];
  const int*   ids   = (const int*)d_in[14];
  float* out = (float*)d_out;

  char* ws = (char*)d_ws;
  u16* cb    = (u16*)(ws + 0ull);             // [32768][768] bf16 (sliced cols), live till fv
  u16* tb    = (u16*)(ws + 50331648ull);      // [32768][768] bf16; VTb reuses after QKV gemm
  u16* wqkvb = (u16*)(ws + 100663296ull);     // [2304][768] bf16
  u16* wob   = (u16*)(ws + 104202240ull);     // [768][768] bf16
  u16* QKVb  = (u16*)(ws + 105381888ull);     // [32768][2304] bf16; aob + stats reuse after attn
  u16* ctxb  = (u16*)(ws + 256376832ull);     // [32768][768] bf16 (attn out)
  u16* VTb   = tb;                             // [64][8][96][512] bf16
  u16* aob   = QKVb;                           // [32768][768] bf16 (gemm2 out)
  float* ssum   = (float*)(ws + 105381888ull + 50331648ull);
  float* ssq    = ssum + 768;
  float* weff   = ssum + 1536;
  float* consts = ssum + 2304;
  float* fv     = (float*)((char*)ssum + 16384ull);

  conv_sliced2<<<dim3(384, 64, 2), 256, 0, stream>>>(
      (const float4*)cols, (const float4*)text, (ushort4*)cb, (ushort4*)tb);
  conv_w<<<2304, 256, 0, stream>>>(
      (const float4*)wq, (const float4*)wk, (const float4*)wvp, (const float4*)wo,
      (ushort4*)wqkvb, (ushort4*)wob);

  // QKV: out [m][2304]; n-tiles 0-2 use cb (Q), 3-8 use tb (K,V)
  gemm256<9, 2304, 3><<<1152, 512, 0, stream>>>(cb, tb, wqkvb, bq, bk, bv, QKVb);
  vtrans<<<dim3(4, 512), 256, 0, stream>>>(QKVb, VTb);
  attn_kernel<<<2048, 256, 0, stream>>>(QKVb, VTb, ctxb);

  zero_kernel<<<6, 256, 0, stream>>>(ssum, 1536);
  gemm256<3, 768, 99><<<384, 512, 0, stream>>>(ctxb, ctxb, wob, bo, bo, bo, aob);
  stats_kernel<<<256, 256, 0, stream>>>(aob, ssum, ssq);
  derived_kernel<<<1, 256, 0, stream>>>(ssum, ssq, w_out, b_out, gamma, beta, weff, consts);
  fv_kernel<<<8176, 256, 0, stream>>>(aob, cb, w_out, weff, consts, fv);
  seg_kernel<<<64, 64, 0, stream>>>(fv, ids, out);
}

// Round 5
// 440.637 us; speedup vs baseline: 1.4125x; 1.0444x over previous
//
#include <hip/hip_runtime.h>
#include <hip/hip_bf16.h>

#define COMMA_IDC 1010
#define NHEAD 8
#define Ll 511
#define Mrows 32704
#define NSEG 17

typedef __attribute__((ext_vector_type(8))) short bf16x8;
typedef __attribute__((ext_vector_type(4))) float f32x4;
typedef unsigned short u16;
typedef unsigned int u32;
typedef unsigned long long u64;

__device__ __forceinline__ u16 f2b(float f) {
  __hip_bfloat16 h = __float2bfloat16(f);
  return *reinterpret_cast<u16*>(&h);
}
__device__ __forceinline__ float b2f(u16 u) {
  u32 x = ((u32)u) << 16;
  return __builtin_bit_cast(float, x);
}

__device__ __forceinline__ void gld_lds16(const void* g, void* l) {
  __builtin_amdgcn_global_load_lds(
      (const __attribute__((address_space(1))) void*)(u64)g,
      (__attribute__((address_space(3))) void*)(u32)(u64)l,
      16, 0, 0);
}

#define MFMA16(a, b, c) __builtin_amdgcn_mfma_f32_16x16x32_bf16(a, b, c, 0, 0, 0)
#define SBAR0 __builtin_amdgcn_sched_barrier(0)

// ---- convert f32 -> bf16, slicing off token 0; z=0: cols->cb, z=1: text->tb
__global__ void conv_sliced2(const float4* __restrict__ s0, const float4* __restrict__ s1,
                             ushort4* __restrict__ d0, ushort4* __restrict__ d1) {
  const float4* src = blockIdx.z ? s1 : s0;
  ushort4* dst = blockIdx.z ? d1 : d0;
  int b = blockIdx.y;
  int idx = blockIdx.x * 256 + threadIdx.x;
  if (idx >= Ll * 192) return;
  int l = idx / 192, c = idx - l * 192;
  float4 v = src[(b * 512 + l + 1) * 192 + c];
  ushort4 o; o.x = f2b(v.x); o.y = f2b(v.y); o.z = f2b(v.z); o.w = f2b(v.w);
  dst[(b * Ll + l) * 192 + c] = o;
}

// ---- all 4 weight matrices in one launch: wq|wk|wv -> wqkvb, wo -> wob
__global__ void conv_w(const float4* __restrict__ wq, const float4* __restrict__ wk,
                       const float4* __restrict__ wv, const float4* __restrict__ wo,
                       ushort4* __restrict__ wqkvb, ushort4* __restrict__ wob) {
  int i = blockIdx.x * 256 + threadIdx.x;   // 0 .. 4*147456
  int seg = i / 147456, off = i - seg * 147456;
  const float4* s = (seg == 0) ? wq : ((seg == 1) ? wk : ((seg == 2) ? wv : wo));
  ushort4* d = (seg == 3) ? wob : (wqkvb + seg * 147456);
  float4 v = s[off];
  ushort4 o; o.x = f2b(v.x); o.y = f2b(v.y); o.z = f2b(v.z); o.w = f2b(v.w);
  d[off] = o;
}

__global__ void zero_kernel(float* p, int n) {
  int i = blockIdx.x * 256 + threadIdx.x;
  if (i < n) p[i] = 0.f;
}

// ============ 256x256x(K=768) bf16 MFMA GEMM, lagged-phase schedule ============
// C = A @ W^T + bias, out [m][NOUT] bf16. W [N][768] row-major.
// 512 thr / 8 waves (2M x 4N), BK=64, 128KB LDS dbuf, chunk-XOR swizzle.
// Each phase issues ds_reads for a FUTURE MFMA cluster; the cluster it runs uses
// phase-old registers, so the compiler's counted lgkmcnt never waits on fresh
// reads and the LDS pipe drains under the MFMA cluster.
#define LDA(db, i, kk) (*(const bf16x8*)(sMem + (db) + wr * 8192 + ((i) * 16 + fr) * 64 + ((((kk) * 4 + fq) ^ xm) << 3)))
#define LDW(db, j, kk) (*(const bf16x8*)(sMem + (db) + 16384 + (((wc * 64 + (j) * 16) >> 7) * 8192) + \
                     (((wc * 64 + (j) * 16) & 127) + fr) * 64 + ((((kk) * 4 + fq) ^ xm) << 3)))

template<int NTILES, int NOUT, int QNT>
__global__ __launch_bounds__(512, 2) void gemm256(
    const u16* __restrict__ A0, const u16* __restrict__ A1, const u16* __restrict__ W,
    const float* __restrict__ b0, const float* __restrict__ b1, const float* __restrict__ b2,
    u16* __restrict__ outp)
{
  __shared__ __align__(16) u16 sMem[65536];  // 128 KB: [buf][A 32K | W 32K]
  const int tid = threadIdx.x;
  const int lane = tid & 63, wid = tid >> 6;
  const int fr = lane & 15, fq = lane >> 4;
  const int wr = wid >> 2, wc = wid & 3;
  const int xm = fr & 7;

  int fid = blockIdx.x;
  int xcd = fid & 7, w = fid >> 3;
  int mrow = xcd * 16 + w / NTILES;
  int ncol = w - (w / NTILES) * NTILES;
  const int m0 = mrow * 256, n0 = ncol * 256;
  const u16* __restrict__ A = (ncol < QNT) ? A0 : A1;

  // staging geometry: thread t covers 16B-chunks t and t+512 of each half-tile.
  // LDS pos (r,p) holds global chunk p^(r&7).
  const int rS = tid >> 3;
  const int cS = (tid & 7) ^ (rS & 7);
  const u16* gA0 = A + (u64)(m0 + rS) * 768 + cS * 8;
  const u16* gA1 = A + (u64)(m0 + 128 + rS) * 768 + cS * 8;
  const u16* gW0 = W + (u64)(n0 + rS) * 768 + cS * 8;
  const u16* gW1 = W + (u64)(n0 + 128 + rS) * 768 + cS * 8;
  const u32 st0 = tid * 8;

  f32x4 acc[8][4] = {};
  bf16x8 afA[4][2], afB[4][2], wfA[2][2], wfB[2][2];

  auto stage_all = [&](int buf, int kt) {
    const int kb = kt * 64;
    const u32 db = (u32)buf * 32768;
    gld_lds16(gA0 + kb, sMem + db + st0);
    gld_lds16(gA0 + kb + 49152, sMem + db + st0 + 4096);
    gld_lds16(gA1 + kb, sMem + db + 8192 + st0);
    gld_lds16(gA1 + kb + 49152, sMem + db + 8192 + st0 + 4096);
    gld_lds16(gW0 + kb, sMem + db + 16384 + st0);
    gld_lds16(gW0 + kb + 49152, sMem + db + 16384 + st0 + 4096);
    gld_lds16(gW1 + kb, sMem + db + 24576 + st0);
    gld_lds16(gW1 + kb + 49152, sMem + db + 24576 + st0 + 4096);
  };

  stage_all(0, 0);

  for (int kt = 0; kt < 12; ++kt) {
    const u32 db = (u32)(kt & 1) * 32768;

    // ---- ph0: reads {afA, wfA} of kt; MFMA M11 of kt-1; then stage kt+1
    asm volatile("s_waitcnt vmcnt(0)" ::: "memory");   // staged loads are ~4 phases old
    SBAR0;
    __builtin_amdgcn_s_barrier();                       // all waves' stage-writes visible
    SBAR0;
#pragma unroll
    for (int i = 0; i < 4; i++) { afA[i][0] = LDA(db, i, 0); afA[i][1] = LDA(db, i, 1); }
#pragma unroll
    for (int j = 0; j < 2; j++) { wfA[j][0] = LDW(db, j, 0); wfA[j][1] = LDW(db, j, 1); }
    if (kt > 0) {
      __builtin_amdgcn_s_setprio(1);
#pragma unroll
      for (int i = 0; i < 4; i++)
#pragma unroll
        for (int j = 0; j < 2; j++) {
          acc[i + 4][j + 2] = MFMA16(afB[i][0], wfB[j][0], acc[i + 4][j + 2]);
          acc[i + 4][j + 2] = MFMA16(afB[i][1], wfB[j][1], acc[i + 4][j + 2]);
        }
      __builtin_amdgcn_s_setprio(0);
    }
    SBAR0;
    __builtin_amdgcn_s_barrier();                       // all waves retired prev-tile reads
    SBAR0;
    if (kt + 1 < 12) stage_all((kt + 1) & 1, kt + 1);   // write opposite buffer
    SBAR0;

    // ---- ph1: reads {wfB}; MFMA M00 (afA x wfA)
#pragma unroll
    for (int j = 0; j < 2; j++) { wfB[j][0] = LDW(db, j + 2, 0); wfB[j][1] = LDW(db, j + 2, 1); }
    __builtin_amdgcn_s_setprio(1);
#pragma unroll
    for (int i = 0; i < 4; i++)
#pragma unroll
      for (int j = 0; j < 2; j++) {
        acc[i][j] = MFMA16(afA[i][0], wfA[j][0], acc[i][j]);
        acc[i][j] = MFMA16(afA[i][1], wfA[j][1], acc[i][j]);
      }
    __builtin_amdgcn_s_setprio(0);
    SBAR0;

    // ---- ph2: reads {afB, wfA'}; MFMA M01 (afA x wfB)
#pragma unroll
    for (int i = 0; i < 4; i++) { afB[i][0] = LDA(db, i + 4, 0); afB[i][1] = LDA(db, i + 4, 1); }
#pragma unroll
    for (int j = 0; j < 2; j++) { wfA[j][0] = LDW(db, j, 0); wfA[j][1] = LDW(db, j, 1); }
    __builtin_amdgcn_s_setprio(1);
#pragma unroll
    for (int i = 0; i < 4; i++)
#pragma unroll
      for (int j = 0; j < 2; j++) {
        acc[i][j + 2] = MFMA16(afA[i][0], wfB[j][0], acc[i][j + 2]);
        acc[i][j + 2] = MFMA16(afA[i][1], wfB[j][1], acc[i][j + 2]);
      }
    __builtin_amdgcn_s_setprio(0);
    SBAR0;

    // ---- ph3: reads {wfB'}; MFMA M10 (afB x wfA')
#pragma unroll
    for (int j = 0; j < 2; j++) { wfB[j][0] = LDW(db, j + 2, 0); wfB[j][1] = LDW(db, j + 2, 1); }
    __builtin_amdgcn_s_setprio(1);
#pragma unroll
    for (int i = 0; i < 4; i++)
#pragma unroll
      for (int j = 0; j < 2; j++) {
        acc[i + 4][j] = MFMA16(afB[i][0], wfA[j][0], acc[i + 4][j]);
        acc[i + 4][j] = MFMA16(afB[i][1], wfA[j][1], acc[i + 4][j]);
      }
    __builtin_amdgcn_s_setprio(0);
    SBAR0;
  }

  // ---- drain: M11 of tile 11
  {
    __builtin_amdgcn_s_setprio(1);
#pragma unroll
    for (int i = 0; i < 4; i++)
#pragma unroll
      for (int j = 0; j < 2; j++) {
        acc[i + 4][j + 2] = MFMA16(afB[i][0], wfB[j][0], acc[i + 4][j + 2]);
        acc[i + 4][j + 2] = MFMA16(afB[i][1], wfB[j][1], acc[i + 4][j + 2]);
      }
    __builtin_amdgcn_s_setprio(0);
  }

  // bias for this block's 256-col slice per 768-col segment
  const float* bp = (n0 < 768) ? b0 : ((n0 < 1536) ? b1 : b2);
  const int bcol = n0 & 767;
  float bj[4];
#pragma unroll
  for (int j = 0; j < 4; j++) bj[j] = bp[bcol + wc * 64 + j * 16 + fr];

  // epilogue: acc -> LDS (stride 264) -> coalesced bf16x8 stores, 2 halves of 128 rows
#pragma unroll
  for (int h = 0; h < 2; h++) {
    __syncthreads();
    if (wr == h) {
#pragma unroll
      for (int i = 0; i < 8; i++)
#pragma unroll
        for (int j = 0; j < 4; j++)
#pragma unroll
          for (int r = 0; r < 4; r++)
            sMem[(i * 16 + fq * 4 + r) * 264 + wc * 64 + j * 16 + fr] = f2b(acc[i][j][r] + bj[j]);
    }
    __syncthreads();
#pragma unroll
    for (int it = 0; it < 8; it++) {
      int chunk = tid + it * 512;
      int lr = chunk >> 5, ch = chunk & 31;
      *(bf16x8*)(outp + (u64)(m0 + h * 128 + lr) * NOUT + n0 + ch * 8) =
          *(const bf16x8*)(sMem + lr * 264 + ch * 8);
    }
  }
}

// ---- V transpose: QKV[m][2304] V-cols -> VT [b,h,96,512], XOR-swizzled LDS tile
__global__ __launch_bounds__(256) void vtrans(const u16* __restrict__ QKV, u16* __restrict__ VT) {
  __shared__ __align__(16) u16 sT[128 * 128];
  int bh = blockIdx.y;
  int b = bh >> 3, h = bh & 7;
  int l0 = blockIdx.x * 128;
  u16* outp = VT + (u64)bh * 96 * 512;
  int t = threadIdx.x;
#pragma unroll
  for (int k = 0; k < 6; k++) {
    int c = t + k * 256;
    int l = c / 12, ch = c - l * 12;
    int lc = l0 + l; if (lc > 510) lc = 510;
    bf16x8 v = *(const bf16x8*)(QKV + (u64)(b * 511 + lc) * 2304 + 1536 + h * 96 + ch * 8);
    int chunk = l * 16 + (ch ^ ((l >> 3) & 7));
    *(bf16x8*)(sT + chunk * 8) = v;
  }
  __syncthreads();
#pragma unroll
  for (int k = 0; k < 6; k++) {
    int c = t + k * 256;
    int d = c >> 4, lch = c & 15;
    u16 vals[8];
#pragma unroll
    for (int k2 = 0; k2 < 8; k2++) {
      int r = lch * 8 + k2;
      int idx = r * 128 + (((d >> 3) ^ (lch & 7)) << 3) + (d & 7);
      vals[k2] = sT[idx];
    }
    bf16x8 o;
#pragma unroll
    for (int k2 = 0; k2 < 8; k2++) o[k2] = (short)vals[k2];
    *(bf16x8*)(outp + (u64)d * 512 + l0 + lch * 8) = o;
  }
}

// ---- flash attention, fixed-max softmax. Block = 128 q rows, 4 waves x 32 q.
#define PST 36
__global__ __launch_bounds__(256) void attn_kernel(
    const u16* __restrict__ QKV, const u16* __restrict__ VT, u16* __restrict__ ctxb)
{
  __shared__ __align__(16) u16 sK[32 * 96];
  __shared__ __align__(16) u16 sV[32 * 96];
  __shared__ __align__(16) u16 sP[4][16 * PST];
  const int tid = threadIdx.x, lane = tid & 63, wid = tid >> 6;
  int fid = blockIdx.x;
  int xcd = fid & 7, slot = (fid >> 3) & 3, grp = fid >> 5;
  int bh = grp * 8 + xcd;
  int b = bh >> 3, h = bh & 7;
  int q0 = slot * 128;
  const int fr = lane & 15, fq = lane >> 4;
  const u64 mb = (u64)(b * 511);
  const u64 hbV = (u64)bh * 96 * 512;

  bf16x8 qf[2][3];
#pragma unroll
  for (int sub = 0; sub < 2; sub++) {
    int qr = q0 + wid * 32 + sub * 16 + fr; if (qr > 510) qr = 510;
#pragma unroll
    for (int ks = 0; ks < 3; ks++)
      qf[sub][ks] = *(const bf16x8*)(QKV + (mb + qr) * 2304 + h * 96 + ks * 32 + fq * 8);
  }

  f32x4 ctx[2][6] = {};
  f32x4 sumP[2] = {};

  int cK1 = wid * 64 + lane;
  int kr1 = cK1 / 12, kc1 = cK1 - kr1 * 12;
  const u16* gK1 = QKV + (mb + kr1) * 2304 + 768 + h * 96 + kc1 * 8;
  int cK2 = 256 + cK1;
  int kr2 = cK2 / 12, kc2 = cK2 - kr2 * 12;
  const u16* gK2 = QKV + (mb + kr2) * 2304 + 768 + h * 96 + kc2 * 8;
  int cV1 = wid * 64 + lane;
  int dV1 = cV1 >> 2, jV1 = (cV1 & 3) ^ ((dV1 >> 1) & 3);
  const u16* gV1 = VT + hbV + (u64)dV1 * 512 + jV1 * 8;
  int cV2 = 256 + (wid - 2) * 64 + lane;
  int dV2 = cV2 >> 2, jV2 = (cV2 & 3) ^ ((dV2 >> 1) & 3);
  const u16* gV2 = VT + hbV + (u64)dV2 * 512 + jV2 * 8;

  u16* lK1 = sK + (u32)(wid * 64) * 8;
  u16* lK2 = sK + (u32)(256 + wid * 64) * 8;
  u16* lV1 = sV + (u32)(wid * 64) * 8;
  u16* lV2 = sV + (u32)(256 + (wid - 2) * 64) * 8;
  u16* pw = &sP[wid][0];

  const float cs = 0.10206207261596575f; // 1/sqrt(96)
  const int cpx = fq ^ ((fr >> 1) & 3);

  for (int kv0 = 0; kv0 < 511; kv0 += 32) {
    __syncthreads();
    gld_lds16(gK1, lK1); gK1 += (u64)32 * 2304;
    if (wid < 2) { gld_lds16(gK2, lK2); gK2 += (u64)32 * 2304; }
    gld_lds16(gV1, lV1); gV1 += 32;
    if (wid >= 2) { gld_lds16(gV2, lV2); gV2 += 32; }
    __syncthreads();

    bf16x8 kf0[3], kf1[3];
#pragma unroll
    for (int ks = 0; ks < 3; ks++) {
      kf0[ks] = *(const bf16x8*)(sK + fr * 96 + ks * 32 + fq * 8);
      kf1[ks] = *(const bf16x8*)(sK + (16 + fr) * 96 + ks * 32 + fq * 8);
    }
    const bool ok1 = (kv0 + 16 + fr) < Ll;

#pragma unroll
    for (int sub = 0; sub < 2; sub++) {
      f32x4 s0 = {}, s1 = {};
#pragma unroll
      for (int ks = 0; ks < 3; ks++) {
        s0 = MFMA16(qf[sub][ks], kf0[ks], s0);
        s1 = MFMA16(qf[sub][ks], kf1[ks], s1);
      }
      float p0[4], p1[4];
#pragma unroll
      for (int r = 0; r < 4; r++) {
        p0[r] = __expf(s0[r] * cs);
        float e1 = __expf(s1[r] * cs);
        p1[r] = ok1 ? e1 : 0.f;
        sumP[sub][r] += p0[r] + p1[r];
      }
#pragma unroll
      for (int r = 0; r < 4; r++) {
        int row = fq * 4 + r;
        pw[row * PST + fr] = f2b(p0[r]);
        pw[row * PST + 16 + fr] = f2b(p1[r]);
      }
      bf16x8 pf = *(const bf16x8*)(pw + fr * PST + fq * 8);
#pragma unroll
      for (int df = 0; df < 6; df++) {
        bf16x8 vf = *(const bf16x8*)(sV + (df * 16 + fr) * 32 + cpx * 8);
        ctx[sub][df] = MFMA16(pf, vf, ctx[sub][df]);
      }
    }
  }

#pragma unroll
  for (int sub = 0; sub < 2; sub++) {
    float inv[4];
#pragma unroll
    for (int r = 0; r < 4; r++) {
      float s = sumP[sub][r];
      s += __shfl_xor(s, 1, 64);
      s += __shfl_xor(s, 2, 64);
      s += __shfl_xor(s, 4, 64);
      s += __shfl_xor(s, 8, 64);
      inv[r] = 1.f / s;
    }
#pragma unroll
    for (int df = 0; df < 6; df++) {
#pragma unroll
      for (int r = 0; r < 4; r++) {
        int q = q0 + wid * 32 + sub * 16 + fq * 4 + r;
        if (q < Ll)
          ctxb[(u64)(b * Ll + q) * 768 + h * 96 + df * 16 + fr] = f2b(ctx[sub][df][r] * inv[r]);
      }
    }
  }
}

// ---- per-channel sums over rows (bf16 input)
__global__ __launch_bounds__(256) void stats_kernel(const u16* __restrict__ ao,
                                                    float* __restrict__ ssum, float* __restrict__ ssq)
{
  int t = threadIdx.x;
  int row0 = blockIdx.x * 128;
  int rowEnd = row0 + 128; if (rowEnd > Mrows) rowEnd = Mrows;
  float s[3] = {0.f, 0.f, 0.f}, q[3] = {0.f, 0.f, 0.f};
  for (int m = row0; m < rowEnd; m++) {
    const u16* rp = ao + (u64)m * 768;
#pragma unroll
    for (int i = 0; i < 3; i++) {
      float v = b2f(rp[t + i * 256]);
      s[i] += v; q[i] += v * v;
    }
  }
#pragma unroll
  for (int i = 0; i < 3; i++) {
    atomicAdd(&ssum[t + i * 256], s[i]);
    atomicAdd(&ssq[t + i * 256], q[i]);
  }
}

__global__ __launch_bounds__(256) void derived_kernel(
    const float* __restrict__ ssum, const float* __restrict__ ssq,
    const float* __restrict__ w_out, const float* __restrict__ b_out,
    const float* __restrict__ gamma, const float* __restrict__ beta,
    float* __restrict__ weff, float* __restrict__ consts)
{
  __shared__ float red[256];
  int t = threadIdx.x;
  float acc = 0.f;
  const float invN = 1.f / 32704.f;
#pragma unroll
  for (int i = 0; i < 3; i++) {
    int hh = t + i * 256;
    float mu = ssum[hh] * invN;
    float var = ssq[hh] * invN - mu * mu;
    float rstd = 1.f / sqrtf(var + 1e-5f);
    float we = w_out[hh] * gamma[hh] * rstd;
    weff[hh] = we;
    acc += w_out[hh] * beta[hh] - we * mu;
  }
  red[t] = acc; __syncthreads();
  for (int s = 128; s > 0; s >>= 1) { if (t < s) red[t] += red[t + s]; __syncthreads(); }
  if (t == 0) consts[0] = b_out[0] + red[0];
}

// ---- fv[m] = dot(c_row, w_out) + dot(a_row, weff) + const   (one wave per row)
__global__ __launch_bounds__(256) void fv_kernel(
    const u16* __restrict__ ao, const u16* __restrict__ cb,
    const float* __restrict__ w_out, const float* __restrict__ weff,
    const float* __restrict__ consts, float* __restrict__ fv)
{
  int lane = threadIdx.x & 63, wid = threadIdx.x >> 6;
  int m = blockIdx.x * 4 + wid;
  if (m >= Mrows) return;
  const u16* ap = ao + (u64)m * 768;
  const u16* cp = cb + (u64)m * 768;
  float acc = 0.f;
#pragma unroll
  for (int i = 0; i < 12; i++) {
    int hh = lane + i * 64;
    acc += b2f(ap[hh]) * weff[hh] + b2f(cp[hh]) * w_out[hh];
  }
#pragma unroll
  for (int off = 1; off < 64; off <<= 1) acc += __shfl_xor(acc, off, 64);
  if (lane == 0) fv[m] = acc + consts[0];
}

// ---- comma-delimited segment means, one wave per batch row
__global__ __launch_bounds__(64) void seg_kernel(
    const float* __restrict__ fv, const int* __restrict__ ids, float* __restrict__ out)
{
  __shared__ float ssum[NSEG];
  __shared__ int scnt[NSEG];
  int lane = threadIdx.x;
  int b = blockIdx.x;
  if (lane < NSEG) { ssum[lane] = 0.f; scnt[lane] = 0; }
  __syncthreads();
  int carry = 0;
  for (int it = 0; it < 8; it++) {
    int l = it * 64 + lane;
    bool active = l < Ll;
    int id = active ? ids[b * 512 + l] : 0;
    bool comma = active && (id == COMMA_IDC);
    u64 cmask = __ballot(comma);
    int seg = carry + __popcll(cmask & ((1ull << lane) - 1ull));
    bool valid = active && (l >= 1) && !comma;
    if (valid && seg < NSEG) {
      atomicAdd(&ssum[seg], fv[b * Ll + l]);
      atomicAdd(&scnt[seg], 1);
    }
    carry += __popcll(cmask);
  }
  __syncthreads();
  if (lane < NSEG) {
    float c = (float)scnt[lane];
    out[b * NSEG + lane] = ssum[lane] / fmaxf(c, 1.f);
  }
}

extern "C" void kernel_launch(void* const* d_in, const int* in_sizes, int n_in,
                              void* d_out, int out_size, void* d_ws, size_t ws_size,
                              hipStream_t stream)
{
  const float* text  = (const float*)d_in[0];
  const float* cols  = (const float*)d_in[1];
  const float* wq    = (const float*)d_in[2];
  const float* wk    = (const float*)d_in[3];
  const float* wvp   = (const float*)d_in[4];
  const float* bq    = (const float*)d_in[5];
  const float* bk    = (const float*)d_in[6];
  const float* bv    = (const float*)d_in[7];
  const float* wo    = (const float*)d_in[8];
  const float* bo    = (const float*)d_in[9];
  const float* gamma = (const float*)d_in[10];
  const float* beta  = (const float*)d_in[11];
  const float* w_out = (const float*)d_in[12];
  const float* b_out = (const float*)d_in[13];
  const int*   ids   = (const int*)d_in[14];
  float* out = (float*)d_out;

  char* ws = (char*)d_ws;
  u16* cb    = (u16*)(ws + 0ull);             // [32768][768] bf16 (sliced cols), live till fv
  u16* tb    = (u16*)(ws + 50331648ull);      // [32768][768] bf16; VTb reuses after QKV gemm
  u16* wqkvb = (u16*)(ws + 100663296ull);     // [2304][768] bf16
  u16* wob   = (u16*)(ws + 104202240ull);     // [768][768] bf16
  u16* QKVb  = (u16*)(ws + 105381888ull);     // [32768][2304] bf16; aob + stats reuse after attn
  u16* ctxb  = (u16*)(ws + 256376832ull);     // [32768][768] bf16 (attn out)
  u16* VTb   = tb;                             // [64][8][96][512] bf16
  u16* aob   = QKVb;                           // [32768][768] bf16 (gemm2 out)
  float* ssum   = (float*)(ws + 105381888ull + 50331648ull);
  float* ssq    = ssum + 768;
  float* weff   = ssum + 1536;
  float* consts = ssum + 2304;
  float* fv     = (float*)((char*)ssum + 16384ull);

  conv_sliced2<<<dim3(384, 64, 2), 256, 0, stream>>>(
      (const float4*)cols, (const float4*)text, (ushort4*)cb, (ushort4*)tb);
  conv_w<<<2304, 256, 0, stream>>>(
      (const float4*)wq, (const float4*)wk, (const float4*)wvp, (const float4*)wo,
      (ushort4*)wqkvb, (ushort4*)wob);

  // QKV: out [m][2304]; n-tiles 0-2 use cb (Q), 3-8 use tb (K,V)
  gemm256<9, 2304, 3><<<1152, 512, 0, stream>>>(cb, tb, wqkvb, bq, bk, bv, QKVb);
  vtrans<<<dim3(4, 512), 256, 0, stream>>>(QKVb, VTb);
  attn_kernel<<<2048, 256, 0, stream>>>(QKVb, VTb, ctxb);

  zero_kernel<<<6, 256, 0, stream>>>(ssum, 1536);
  gemm256<3, 768, 99><<<384, 512, 0, stream>>>(ctxb, ctxb, wob, bo, bo, bo, aob);
  stats_kernel<<<256, 256, 0, stream>>>(aob, ssum, ssq);
  derived_kernel<<<1, 256, 0, stream>>>(ssum, ssq, w_out, b_out, gamma, beta, weff, consts);
  fv_kernel<<<8176, 256, 0, stream>>>(aob, cb, w_out, weff, consts, fv);
  seg_kernel<<<64, 64, 0, stream>>>(fv, ids, out);
}